// Round 1
// baseline (534.597 us; speedup 1.0000x reference)
//
#include <hip/hip_runtime.h>
#include <hip/hip_bf16.h>

typedef unsigned short u16;
typedef unsigned int u32;
typedef __attribute__((ext_vector_type(4))) float f32x4;
typedef __attribute__((ext_vector_type(8))) short s16x8;

__device__ __forceinline__ u16 f2bf(float f) {
    union { float f; u32 u; } v; v.f = f;
    u32 r = v.u + 0x7FFFu + ((v.u >> 16) & 1u);
    return (u16)(r >> 16);
}
__device__ __forceinline__ float bf2f(u16 h) {
    union { u32 u; float f; } v; v.u = ((u32)h) << 16;
    return v.f;
}

__device__ __forceinline__ void gll16(const void* g, void* l) {
    __builtin_amdgcn_global_load_lds(
        (const __attribute__((address_space(1))) void*)g,
        (__attribute__((address_space(3))) void*)l, 16, 0, 0);
}

// ---------------- prep kernels ----------------

// x [4194304] f32 -> hi/lo bf16 (as u16), float4-vectorized
__global__ __launch_bounds__(256) void split_x_kernel(
    const float* __restrict__ x, u16* __restrict__ hi, u16* __restrict__ lo) {
    int i = blockIdx.x * 256 + threadIdx.x;       // < 1048576 (float4 count)
    float4 v = ((const float4*)x)[i];
    u16 h0 = f2bf(v.x), h1 = f2bf(v.y), h2 = f2bf(v.z), h3 = f2bf(v.w);
    ushort4 h, l;
    h.x = h0; h.y = h1; h.z = h2; h.w = h3;
    l.x = f2bf(v.x - bf2f(h0)); l.y = f2bf(v.y - bf2f(h1));
    l.z = f2bf(v.z - bf2f(h2)); l.w = f2bf(v.w - bf2f(h3));
    ((ushort4*)hi)[i] = h; ((ushort4*)lo)[i] = l;
}

// transpose + split the 4 weight matrices into [N][K] layout
// y=0: Wq1 [256][512] -> w1hi/lo + 0      ([512][256])
// y=1: Wk1 [256][512] -> w1hi/lo + 131072
// y=2: Wq2 [512][256] -> w2hi/lo + 0      ([256][512])
// y=3: Wk2 [512][256] -> w2hi/lo + 131072
__global__ __launch_bounds__(256) void split_wT_kernel(
    const float* __restrict__ Wq1, const float* __restrict__ Wk1,
    const float* __restrict__ Wq2, const float* __restrict__ Wk2,
    u16* __restrict__ w1hi, u16* __restrict__ w1lo,
    u16* __restrict__ w2hi, u16* __restrict__ w2lo) {
    int y = blockIdx.y;
    const float* src = (y == 0) ? Wq1 : (y == 1) ? Wk1 : (y == 2) ? Wq2 : Wk2;
    int R = (y < 2) ? 256 : 512;   // src rows = K of GEMM
    int C = (y < 2) ? 512 : 256;   // src cols = N of GEMM
    u16* dh = ((y < 2) ? w1hi : w2hi) + (y & 1) * 131072;
    u16* dl = ((y < 2) ? w1lo : w2lo) + (y & 1) * 131072;
    int i = blockIdx.x * 256 + threadIdx.x;       // < 131072
    int c = i / R, r = i - c * R;                 // out[c][r] = src[r][c]
    float v = src[(size_t)r * C + c];
    u16 h = f2bf(v);
    dh[i] = h; dl[i] = f2bf(v - bf2f(h));
}

__global__ void pack_bias(const float* __restrict__ bq1, const float* __restrict__ bk1,
                          const float* __restrict__ bq2, const float* __restrict__ bk2,
                          float* __restrict__ b1, float* __restrict__ b2) {
    int t = threadIdx.x;                           // 512 threads
    b1[t] = bq1[t]; b1[512 + t] = bk1[t];
    if (t < 256) { b2[t] = bq2[t]; b2[256 + t] = bk2[t]; }
}

// ---------------- split-bf16 GEMM: C[M,N] = A[M,K] * B[N,K]^T ----------------
// A,B given as (hi,lo) bf16 pairs; D ~= Ahi*Bhi + Ahi*Blo + Alo*Bhi  (fp32-grade)
// SPLIT_OUT: epilogue adds bias, optional relu, writes (hi,lo) bf16 pair
// else: writes raw fp32 C.
#define BM 128
#define BN 128
#define BK 64

template<int SPLIT_OUT, int RELU>
__global__ __launch_bounds__(256, 2)
void gemm_bt(const u16* __restrict__ Ahi, const u16* __restrict__ Alo,
             const u16* __restrict__ Bhi, const u16* __restrict__ Blo,
             const float* __restrict__ bias, long biasBatch,
             float* __restrict__ Cf, u16* __restrict__ Chi, u16* __restrict__ Clo,
             int M, int N, int K,
             long aBatch, long bBatch, long cBatch) {
    __shared__ u16 lds[4 * BM * BK];   // Ahi | Alo | Bhi | Blo tiles, 16KB each
    const int tid = threadIdx.x;
    const int wave = tid >> 6, lane = tid & 63;
    const int bz = blockIdx.z;
    const long m0 = (long)blockIdx.y * BM, n0 = (long)blockIdx.x * BN;

    const u16* pAhi = Ahi + (size_t)bz * aBatch;
    const u16* pAlo = Alo + (size_t)bz * aBatch;
    const u16* pBhi = Bhi + (size_t)bz * bBatch;
    const u16* pBlo = Blo + (size_t)bz * bBatch;

    // staging geometry: tile is [128 rows][64 k] bf16 = 16KB, linear.
    // wave w covers bytes [w*4096, (w+1)*4096) in 4 instrs of 1KB (64 lanes x 16B)
    int srow[4], scol[4];
#pragma unroll
    for (int i = 0; i < 4; i++) {
        int lin = wave * 4096 + i * 1024 + lane * 16;  // byte offset in tile
        srow[i] = lin >> 7;            // row 0..127
        scol[i] = (lin & 127) >> 1;    // u16 index 0..63 within row
    }

    const int wr = wave >> 1, wc = wave & 1;
    const int lrow = lane & 15, kgrp = lane >> 4;

    f32x4 acc[4][4] = {};

    const int ksteps = K / BK;
    for (int kt = 0; kt < ksteps; ++kt) {
#pragma unroll
        for (int i = 0; i < 4; i++) {
            size_t ga = (size_t)(m0 + srow[i]) * K + (size_t)kt * BK + scol[i];
            size_t gb = (size_t)(n0 + srow[i]) * K + (size_t)kt * BK + scol[i];
            u32 lb = (u32)(wave * 4096 + i * 1024);    // wave-uniform LDS byte base
            gll16(pAhi + ga, (char*)lds + 0 * 16384 + lb);
            gll16(pAlo + ga, (char*)lds + 1 * 16384 + lb);
            gll16(pBhi + gb, (char*)lds + 2 * 16384 + lb);
            gll16(pBlo + gb, (char*)lds + 3 * 16384 + lb);
        }
        __syncthreads();
#pragma unroll
        for (int kk = 0; kk < 2; ++kk) {
            s16x8 ah[4], al[4], bh[4], bl[4];
            const int ko = kk * 32 + kgrp * 8;
#pragma unroll
            for (int m = 0; m < 4; m++) {
                int r = wr * 64 + m * 16 + lrow;
                ah[m] = *(const s16x8*)&lds[0 * 8192 + r * 64 + ko];
                al[m] = *(const s16x8*)&lds[1 * 8192 + r * 64 + ko];
            }
#pragma unroll
            for (int n = 0; n < 4; n++) {
                int r = wc * 64 + n * 16 + lrow;
                bh[n] = *(const s16x8*)&lds[2 * 8192 + r * 64 + ko];
                bl[n] = *(const s16x8*)&lds[3 * 8192 + r * 64 + ko];
            }
#pragma unroll
            for (int m = 0; m < 4; m++)
#pragma unroll
                for (int n = 0; n < 4; n++) {
                    acc[m][n] = __builtin_amdgcn_mfma_f32_16x16x32_bf16(ah[m], bh[n], acc[m][n], 0, 0, 0);
                    acc[m][n] = __builtin_amdgcn_mfma_f32_16x16x32_bf16(ah[m], bl[n], acc[m][n], 0, 0, 0);
                    acc[m][n] = __builtin_amdgcn_mfma_f32_16x16x32_bf16(al[m], bh[n], acc[m][n], 0, 0, 0);
                }
        }
        __syncthreads();
    }

    // epilogue: C/D layout col=lane&15, row=(lane>>4)*4+j  [guide §3, m89-verified]
#pragma unroll
    for (int m = 0; m < 4; m++) {
#pragma unroll
        for (int n = 0; n < 4; n++) {
            long col = n0 + wc * 64 + n * 16 + lrow;
            float bv = 0.f;
            if (SPLIT_OUT) bv = bias[bz * biasBatch + col];
#pragma unroll
            for (int j = 0; j < 4; j++) {
                long row = m0 + wr * 64 + m * 16 + kgrp * 4 + j;
                float v = acc[m][n][j];
                if (SPLIT_OUT) {
                    v += bv;
                    if (RELU) v = fmaxf(v, 0.f);
                    u16 h = f2bf(v);
                    size_t o = (size_t)bz * cBatch + (size_t)row * N + col;
                    Chi[o] = h;
                    Clo[o] = f2bf(v - bf2f(h));
                } else {
                    Cf[(size_t)bz * cBatch + (size_t)row * N + col] = v;
                }
            }
        }
    }
}

// ---------------- row softmax: dist = softmax(10*S/rowmax) in place ----------------
__global__ __launch_bounds__(256) void softmax_rows(float* __restrict__ S) {
    const int tid = threadIdx.x;
    float* p = S + (size_t)blockIdx.x * 4096;
    float4 v[4];
    float lmax = -3.4e38f;
#pragma unroll
    for (int i = 0; i < 4; i++) {
        v[i] = ((float4*)p)[tid + 256 * i];
        lmax = fmaxf(lmax, fmaxf(fmaxf(v[i].x, v[i].y), fmaxf(v[i].z, v[i].w)));
    }
#pragma unroll
    for (int o = 32; o; o >>= 1) lmax = fmaxf(lmax, __shfl_xor(lmax, o));
    __shared__ float redm[4];
    __shared__ float reds[4];
    if ((tid & 63) == 0) redm[tid >> 6] = lmax;
    __syncthreads();
    const float m = fmaxf(fmaxf(redm[0], redm[1]), fmaxf(redm[2], redm[3]));
    const float c = 10.0f / m;     // logit = c*s; max logit = 10
    float s = 0.f;
#pragma unroll
    for (int i = 0; i < 4; i++) {
        v[i].x = expf(c * v[i].x - 10.0f);
        v[i].y = expf(c * v[i].y - 10.0f);
        v[i].z = expf(c * v[i].z - 10.0f);
        v[i].w = expf(c * v[i].w - 10.0f);
        s += v[i].x + v[i].y + v[i].z + v[i].w;
    }
#pragma unroll
    for (int o = 32; o; o >>= 1) s += __shfl_xor(s, o);
    if ((tid & 63) == 0) reds[tid >> 6] = s;
    __syncthreads();
    const float inv = 1.0f / (reds[0] + reds[1] + reds[2] + reds[3]);
#pragma unroll
    for (int i = 0; i < 4; i++) {
        v[i].x *= inv; v[i].y *= inv; v[i].z *= inv; v[i].w *= inv;
        ((float4*)p)[tid + 256 * i] = v[i];
    }
}

// ---------------- launch ----------------
extern "C" void kernel_launch(void* const* d_in, const int* in_sizes, int n_in,
                              void* d_out, int out_size, void* d_ws, size_t ws_size,
                              hipStream_t stream) {
    const float* x   = (const float*)d_in[0];
    const float* Wq1 = (const float*)d_in[1];
    const float* bq1 = (const float*)d_in[2];
    const float* Wq2 = (const float*)d_in[3];
    const float* bq2 = (const float*)d_in[4];
    const float* Wk1 = (const float*)d_in[5];
    const float* bk1 = (const float*)d_in[6];
    const float* Wk2 = (const float*)d_in[7];
    const float* bk2 = (const float*)d_in[8];
    float* out = (float*)d_out;

    const size_t MB = 1048576;
    char* ws = (char*)d_ws;
    // ws layout (~34.01 MB): qhi | khi | qlo | klo | weights | biases
    u16* qhi  = (u16*)(ws + 0 * MB);
    u16* khi  = (u16*)(ws + 8 * MB);
    u16* qlo  = (u16*)(ws + 16 * MB);
    u16* klo  = (u16*)(ws + 24 * MB);
    u16* w1hi = (u16*)(ws + 32 * MB);
    u16* w1lo = (u16*)(ws + 32 * MB + 512 * 1024);
    u16* w2hi = (u16*)(ws + 33 * MB);
    u16* w2lo = (u16*)(ws + 33 * MB + 512 * 1024);
    float* b1 = (float*)(ws + 34 * MB);
    float* b2 = (float*)(ws + 34 * MB + 4096);

    // d_out doubles as scratch before QK^T overwrites it:
    char* ob = (char*)d_out;
    u16* xhi = (u16*)(ob + 0 * MB);    // 8MB
    u16* xlo = (u16*)(ob + 8 * MB);    // 8MB
    u16* Hhi = (u16*)(ob + 16 * MB);   // [2][16384][512] = 32MB
    u16* Hlo = (u16*)(ob + 48 * MB);   // 32MB

    split_x_kernel<<<4096, 256, 0, stream>>>(x, xhi, xlo);
    split_wT_kernel<<<dim3(512, 4), 256, 0, stream>>>(Wq1, Wk1, Wq2, Wk2,
                                                      w1hi, w1lo, w2hi, w2lo);
    pack_bias<<<1, 512, 0, stream>>>(bq1, bk1, bq2, bk2, b1, b2);

    // layer 1 (both branches): H = relu(x*W1 + b1)  [16384,512], split output
    gemm_bt<1, 1><<<dim3(4, 128, 2), 256, 0, stream>>>(
        xhi, xlo, w1hi, w1lo, b1, 512,
        nullptr, Hhi, Hlo,
        16384, 512, 256,
        0L, 131072L, 8388608L);

    // layer 2 (both branches): Q/K = H*W2 + b2  [16384,256], split output into ws
    gemm_bt<1, 0><<<dim3(2, 128, 2), 256, 0, stream>>>(
        Hhi, Hlo, w2hi, w2lo, b2, 256,
        nullptr, qhi, qlo,
        16384, 256, 512,
        8388608L, 131072L, 4194304L);

    // S = Q*K^T per batch -> raw fp32 into d_out
    gemm_bt<0, 0><<<dim3(32, 32, 4), 256, 0, stream>>>(
        qhi, qlo, khi, klo, nullptr, 0,
        out, nullptr, nullptr,
        4096, 4096, 256,
        1048576L, 1048576L, 16777216L);

    // softmax(10*S/rowmax) per row, in place
    softmax_rows<<<16384, 256, 0, stream>>>(out);
}

// Round 4
// 472.884 us; speedup vs baseline: 1.1305x; 1.1305x over previous
//
#include <hip/hip_runtime.h>
#include <hip/hip_bf16.h>

typedef unsigned short u16;
typedef unsigned int u32;
typedef _Float16 f16;
typedef __attribute__((ext_vector_type(4))) float f32x4;
typedef __attribute__((ext_vector_type(8))) short s16x8;
typedef __attribute__((ext_vector_type(8))) _Float16 f16x8;

__device__ __forceinline__ u16 f2bf(float f) {
    union { float f; u32 u; } v; v.f = f;
    u32 r = v.u + 0x7FFFu + ((v.u >> 16) & 1u);
    return (u16)(r >> 16);
}
__device__ __forceinline__ float bf2f(u16 h) {
    union { u32 u; float f; } v; v.u = ((u32)h) << 16;
    return v.f;
}

__device__ __forceinline__ void gll16(const void* g, void* l) {
    __builtin_amdgcn_global_load_lds(
        (const __attribute__((address_space(1))) void*)g,
        (__attribute__((address_space(3))) void*)l, 16, 0, 0);
}

// ---------------- prep kernels ----------------

__global__ __launch_bounds__(256) void split_x_kernel(
    const float* __restrict__ x, u16* __restrict__ hi, u16* __restrict__ lo) {
    int i = blockIdx.x * 256 + threadIdx.x;       // < 1048576 (float4 count)
    float4 v = ((const float4*)x)[i];
    u16 h0 = f2bf(v.x), h1 = f2bf(v.y), h2 = f2bf(v.z), h3 = f2bf(v.w);
    ushort4 h, l;
    h.x = h0; h.y = h1; h.z = h2; h.w = h3;
    l.x = f2bf(v.x - bf2f(h0)); l.y = f2bf(v.y - bf2f(h1));
    l.z = f2bf(v.z - bf2f(h2)); l.w = f2bf(v.w - bf2f(h3));
    ((ushort4*)hi)[i] = h; ((ushort4*)lo)[i] = l;
}

// transpose + split the 4 weight matrices into [N][K] layout
__global__ __launch_bounds__(256) void split_wT_kernel(
    const float* __restrict__ Wq1, const float* __restrict__ Wk1,
    const float* __restrict__ Wq2, const float* __restrict__ Wk2,
    u16* __restrict__ w1hi, u16* __restrict__ w1lo,
    u16* __restrict__ w2hi, u16* __restrict__ w2lo) {
    int y = blockIdx.y;
    const float* src = (y == 0) ? Wq1 : (y == 1) ? Wk1 : (y == 2) ? Wq2 : Wk2;
    int R = (y < 2) ? 256 : 512;   // src rows = K of GEMM
    int C = (y < 2) ? 512 : 256;   // src cols = N of GEMM
    u16* dh = ((y < 2) ? w1hi : w2hi) + (y & 1) * 131072;
    u16* dl = ((y < 2) ? w1lo : w2lo) + (y & 1) * 131072;
    int i = blockIdx.x * 256 + threadIdx.x;       // < 131072
    int c = i / R, r = i - c * R;                 // out[c][r] = src[r][c]
    float v = src[(size_t)r * C + c];
    u16 h = f2bf(v);
    dh[i] = h; dl[i] = f2bf(v - bf2f(h));
}

__global__ void pack_bias(const float* __restrict__ bq1, const float* __restrict__ bk1,
                          const float* __restrict__ bq2, const float* __restrict__ bk2,
                          float* __restrict__ b1, float* __restrict__ b2) {
    int t = threadIdx.x;                           // 512 threads
    b1[t] = bq1[t]; b1[512 + t] = bk1[t];
    if (t < 256) { b2[t] = bq2[t]; b2[256 + t] = bk2[t]; }
}

// ---------------- split-bf16 GEMM: C[M,N] = A[M,K] * B[N,K]^T ----------------
// A always (hi,lo). SPLITB: B also (hi,lo) -> 3 MFMAs (hh+hl+lh). else 2 (hh+lh).
// SPLIT_OUT: bias+optional relu, write (hi,lo) bf16. else raw C (F16S ? fp16 : fp32).
#define BM 128
#define BN 128
#define BK 64

template<int SPLIT_OUT, int RELU, int SPLITB, int F16S>
__global__ __launch_bounds__(256, 2)
void gemm_bt(const u16* __restrict__ Ahi, const u16* __restrict__ Alo,
             const u16* __restrict__ Bhi, const u16* __restrict__ Blo,
             const float* __restrict__ bias, long biasBatch,
             void* __restrict__ Cout, u16* __restrict__ Chi, u16* __restrict__ Clo,
             int M, int N, int K,
             long aBatch, long bBatch, long cBatch) {
    __shared__ u16 lds[(3 + SPLITB) * BM * BK];   // Ahi | Alo | Bhi | [Blo], 16KB each
    const int tid = threadIdx.x;
    const int wave = tid >> 6, lane = tid & 63;
    const int bz = blockIdx.z;
    const long m0 = (long)blockIdx.y * BM, n0 = (long)blockIdx.x * BN;

    const u16* pAhi = Ahi + (size_t)bz * aBatch;
    const u16* pAlo = Alo + (size_t)bz * aBatch;
    const u16* pBhi = Bhi + (size_t)bz * bBatch;
    const u16* pBlo = Blo + (size_t)bz * bBatch;

    // staging geometry: tile is [128 rows][64 k] bf16 = 16KB, linear.
    int srow[4], scol[4];
#pragma unroll
    for (int i = 0; i < 4; i++) {
        int lin = wave * 4096 + i * 1024 + lane * 16;  // byte offset in tile
        srow[i] = lin >> 7;            // row 0..127
        scol[i] = (lin & 127) >> 1;    // u16 index 0..63 within row
    }

    const int wr = wave >> 1, wc = wave & 1;
    const int lrow = lane & 15, kgrp = lane >> 4;

    f32x4 acc[4][4] = {};

    const int ksteps = K / BK;
    for (int kt = 0; kt < ksteps; ++kt) {
#pragma unroll
        for (int i = 0; i < 4; i++) {
            size_t ga = (size_t)(m0 + srow[i]) * K + (size_t)kt * BK + scol[i];
            size_t gb = (size_t)(n0 + srow[i]) * K + (size_t)kt * BK + scol[i];
            u32 lb = (u32)(wave * 4096 + i * 1024);    // wave-uniform LDS byte base
            gll16(pAhi + ga, (char*)lds + 0 * 16384 + lb);
            gll16(pAlo + ga, (char*)lds + 1 * 16384 + lb);
            gll16(pBhi + gb, (char*)lds + 2 * 16384 + lb);
            if constexpr (SPLITB) gll16(pBlo + gb, (char*)lds + 3 * 16384 + lb);
        }
        __syncthreads();
#pragma unroll
        for (int kk = 0; kk < 2; ++kk) {
            s16x8 ah[4], al[4], bh[4], bl[4];
            const int ko = kk * 32 + kgrp * 8;
#pragma unroll
            for (int m = 0; m < 4; m++) {
                int r = wr * 64 + m * 16 + lrow;
                ah[m] = *(const s16x8*)&lds[0 * 8192 + r * 64 + ko];
                al[m] = *(const s16x8*)&lds[1 * 8192 + r * 64 + ko];
            }
#pragma unroll
            for (int n = 0; n < 4; n++) {
                int r = wc * 64 + n * 16 + lrow;
                bh[n] = *(const s16x8*)&lds[2 * 8192 + r * 64 + ko];
                if constexpr (SPLITB) bl[n] = *(const s16x8*)&lds[3 * 8192 + r * 64 + ko];
            }
#pragma unroll
            for (int m = 0; m < 4; m++)
#pragma unroll
                for (int n = 0; n < 4; n++) {
                    acc[m][n] = __builtin_amdgcn_mfma_f32_16x16x32_bf16(ah[m], bh[n], acc[m][n], 0, 0, 0);
                    if constexpr (SPLITB)
                        acc[m][n] = __builtin_amdgcn_mfma_f32_16x16x32_bf16(ah[m], bl[n], acc[m][n], 0, 0, 0);
                    acc[m][n] = __builtin_amdgcn_mfma_f32_16x16x32_bf16(al[m], bh[n], acc[m][n], 0, 0, 0);
                }
        }
        __syncthreads();
    }

    // epilogue: C/D layout col=lane&15, row=(lane>>4)*4+j  [guide §3, m89-verified]
#pragma unroll
    for (int m = 0; m < 4; m++) {
#pragma unroll
        for (int n = 0; n < 4; n++) {
            long col = n0 + wc * 64 + n * 16 + lrow;
            float bv = 0.f;
            if (SPLIT_OUT) bv = bias[bz * biasBatch + col];
#pragma unroll
            for (int j = 0; j < 4; j++) {
                long row = m0 + wr * 64 + m * 16 + kgrp * 4 + j;
                float v = acc[m][n][j];
                size_t o = (size_t)bz * cBatch + (size_t)row * N + col;
                if constexpr (SPLIT_OUT) {
                    v += bv;
                    if (RELU) v = fmaxf(v, 0.f);
                    u16 h = f2bf(v);
                    Chi[o] = h;
                    Clo[o] = f2bf(v - bf2f(h));
                } else if constexpr (F16S) {
                    ((f16*)Cout)[o] = (f16)v;
                } else {
                    ((float*)Cout)[o] = v;
                }
            }
        }
    }
}

// ---------------- softmax: dist = softmax(10*S/rowmax) ----------------
// fp32 in-place variant
__global__ __launch_bounds__(256) void softmax_rows(float* __restrict__ S) {
    const int tid = threadIdx.x;
    float* p = S + (size_t)blockIdx.x * 4096;
    float4 v[4];
    float lmax = -3.4e38f;
#pragma unroll
    for (int i = 0; i < 4; i++) {
        v[i] = ((float4*)p)[tid + 256 * i];
        lmax = fmaxf(lmax, fmaxf(fmaxf(v[i].x, v[i].y), fmaxf(v[i].z, v[i].w)));
    }
#pragma unroll
    for (int o = 32; o; o >>= 1) lmax = fmaxf(lmax, __shfl_xor(lmax, o));
    __shared__ float redm[4];
    __shared__ float reds[4];
    if ((tid & 63) == 0) redm[tid >> 6] = lmax;
    __syncthreads();
    const float m = fmaxf(fmaxf(redm[0], redm[1]), fmaxf(redm[2], redm[3]));
    const float c = 10.0f / m;
    float s = 0.f;
#pragma unroll
    for (int i = 0; i < 4; i++) {
        v[i].x = expf(c * v[i].x - 10.0f);
        v[i].y = expf(c * v[i].y - 10.0f);
        v[i].z = expf(c * v[i].z - 10.0f);
        v[i].w = expf(c * v[i].w - 10.0f);
        s += v[i].x + v[i].y + v[i].z + v[i].w;
    }
#pragma unroll
    for (int o = 32; o; o >>= 1) s += __shfl_xor(s, o);
    if ((tid & 63) == 0) reds[tid >> 6] = s;
    __syncthreads();
    const float inv = 1.0f / (reds[0] + reds[1] + reds[2] + reds[3]);
#pragma unroll
    for (int i = 0; i < 4; i++) {
        v[i].x *= inv; v[i].y *= inv; v[i].z *= inv; v[i].w *= inv;
        ((float4*)p)[tid + 256 * i] = v[i];
    }
}

// fp16-S variant: read fp16 S from ws, write fp32 dist to d_out
__global__ __launch_bounds__(256) void softmax_f16(const f16* __restrict__ S,
                                                   float* __restrict__ O) {
    const int tid = threadIdx.x;
    const f16* p = S + (size_t)blockIdx.x * 4096;
    float* o = O + (size_t)blockIdx.x * 4096;
    f16x8 a0 = ((const f16x8*)p)[tid];          // elements 8*tid ..
    f16x8 a1 = ((const f16x8*)p)[tid + 256];    // elements 8*(tid+256) ..
    float v[16];
#pragma unroll
    for (int j = 0; j < 8; j++) { v[j] = (float)a0[j]; v[8 + j] = (float)a1[j]; }
    float lmax = -3.4e38f;
#pragma unroll
    for (int j = 0; j < 16; j++) lmax = fmaxf(lmax, v[j]);
#pragma unroll
    for (int off = 32; off; off >>= 1) lmax = fmaxf(lmax, __shfl_xor(lmax, off));
    __shared__ float redm[4];
    __shared__ float reds[4];
    if ((tid & 63) == 0) redm[tid >> 6] = lmax;
    __syncthreads();
    const float m = fmaxf(fmaxf(redm[0], redm[1]), fmaxf(redm[2], redm[3]));
    const float c = 10.0f / m;
    float s = 0.f;
#pragma unroll
    for (int j = 0; j < 16; j++) { v[j] = expf(c * v[j] - 10.0f); s += v[j]; }
#pragma unroll
    for (int off = 32; off; off >>= 1) s += __shfl_xor(s, off);
    if ((tid & 63) == 0) reds[tid >> 6] = s;
    __syncthreads();
    const float inv = 1.0f / (reds[0] + reds[1] + reds[2] + reds[3]);
    float4 w;
#pragma unroll
    for (int q = 0; q < 4; q++) {
        int base = q * 4;
        w.x = v[base + 0] * inv; w.y = v[base + 1] * inv;
        w.z = v[base + 2] * inv; w.w = v[base + 3] * inv;
        // elements 8*tid+4q  -> float4 index 2*tid+q (q<2) ; 8*(tid+256)+4(q-2) -> 2*tid+512+(q-2)
        int idx = (q < 2) ? (2 * tid + q) : (2 * tid + 512 + (q - 2));
        ((float4*)o)[idx] = w;
    }
}

// ---------------- launch ----------------
extern "C" void kernel_launch(void* const* d_in, const int* in_sizes, int n_in,
                              void* d_out, int out_size, void* d_ws, size_t ws_size,
                              hipStream_t stream) {
    const float* x   = (const float*)d_in[0];
    const float* Wq1 = (const float*)d_in[1];
    const float* bq1 = (const float*)d_in[2];
    const float* Wq2 = (const float*)d_in[3];
    const float* bq2 = (const float*)d_in[4];
    const float* Wk1 = (const float*)d_in[5];
    const float* bk1 = (const float*)d_in[6];
    const float* Wk2 = (const float*)d_in[7];
    const float* bk2 = (const float*)d_in[8];
    float* out = (float*)d_out;

    const size_t MB = 1048576;
    char* ws = (char*)d_ws;
    // ws layout: biases | weights | Q/K splits | [S fp16]
    float* b1 = (float*)(ws);                    // 4KB
    float* b2 = (float*)(ws + 4096);             // 2KB (reserve to 8KB)
    u16* w1hi = (u16*)(ws + 8 * 1024);           // 512KB
    u16* w1lo = (u16*)(ws + 8 * 1024 + 512 * 1024);
    u16* w2hi = (u16*)(ws + 8 * 1024 + 1024 * 1024);
    u16* w2lo = (u16*)(ws + 8 * 1024 + 1536 * 1024);
    u16* qhi  = (u16*)(ws + 4 * MB);             // 8MB
    u16* khi  = (u16*)(ws + 12 * MB);            // 8MB
    u16* qlo  = (u16*)(ws + 20 * MB);            // 8MB
    u16* klo  = (u16*)(ws + 28 * MB);            // 8MB (written, unused by QK^T)
    f16* S16  = (f16*)(ws + 36 * MB);            // 128MB if available

    const bool f16s = (ws_size >= 164 * MB);

    // d_out doubles as scratch before QK^T/softmax overwrites it:
    char* ob = (char*)d_out;
    u16* xhi = (u16*)(ob + 0 * MB);    // 8MB
    u16* xlo = (u16*)(ob + 8 * MB);    // 8MB
    u16* Hhi = (u16*)(ob + 16 * MB);   // [2][16384][512] = 32MB
    u16* Hlo = (u16*)(ob + 48 * MB);   // 32MB

    split_x_kernel<<<4096, 256, 0, stream>>>(x, xhi, xlo);
    split_wT_kernel<<<dim3(512, 4), 256, 0, stream>>>(Wq1, Wk1, Wq2, Wk2,
                                                      w1hi, w1lo, w2hi, w2lo);
    pack_bias<<<1, 512, 0, stream>>>(bq1, bk1, bq2, bk2, b1, b2);

    // layer 1 (both branches): H = relu(x*W1 + b1)  [16384,512], split output
    gemm_bt<1, 1, 1, 0><<<dim3(4, 128, 2), 256, 0, stream>>>(
        xhi, xlo, w1hi, w1lo, b1, 512,
        nullptr, Hhi, Hlo,
        16384, 512, 256,
        0L, 131072L, 8388608L);

    // layer 2 (both branches): Q/K = H*W2 + b2  [16384,256], split output into ws
    gemm_bt<1, 0, 1, 0><<<dim3(2, 128, 2), 256, 0, stream>>>(
        Hhi, Hlo, w2hi, w2lo, b2, 256,
        nullptr, qhi, qlo,
        16384, 256, 512,
        8388608L, 131072L, 4194304L);

    // S = Q*K^T per batch: A split, B = khi only (2-MFMA)
    if (f16s) {
        gemm_bt<0, 0, 0, 1><<<dim3(32, 32, 4), 256, 0, stream>>>(
            qhi, qlo, khi, klo, nullptr, 0,
            (void*)S16, nullptr, nullptr,
            4096, 4096, 256,
            1048576L, 1048576L, 16777216L);
        softmax_f16<<<16384, 256, 0, stream>>>(S16, out);
    } else {
        gemm_bt<0, 0, 0, 0><<<dim3(32, 32, 4), 256, 0, stream>>>(
            qhi, qlo, khi, klo, nullptr, 0,
            (void*)out, nullptr, nullptr,
            4096, 4096, 256,
            1048576L, 1048576L, 16777216L);
        softmax_rows<<<16384, 256, 0, stream>>>(out);
    }
}

// Round 6
// 468.747 us; speedup vs baseline: 1.1405x; 1.0088x over previous
//
#include <hip/hip_runtime.h>
#include <hip/hip_bf16.h>

typedef unsigned short u16;
typedef unsigned int u32;
typedef _Float16 f16;
typedef __attribute__((ext_vector_type(4))) float f32x4;
typedef __attribute__((ext_vector_type(8))) short s16x8;
typedef __attribute__((ext_vector_type(8))) _Float16 f16x8;

__device__ __forceinline__ u16 f2bf(float f) {
    union { float f; u32 u; } v; v.f = f;
    u32 r = v.u + 0x7FFFu + ((v.u >> 16) & 1u);
    return (u16)(r >> 16);
}
__device__ __forceinline__ float bf2f(u16 h) {
    union { u32 u; float f; } v; v.u = ((u32)h) << 16;
    return v.f;
}

__device__ __forceinline__ void gll16(const void* g, void* l) {
    __builtin_amdgcn_global_load_lds(
        (const __attribute__((address_space(1))) void*)g,
        (__attribute__((address_space(3))) void*)l, 16, 0, 0);
}

// ---------------- prep kernels ----------------

__global__ __launch_bounds__(256) void split_x_kernel(
    const float* __restrict__ x, u16* __restrict__ hi, u16* __restrict__ lo) {
    int i = blockIdx.x * 256 + threadIdx.x;       // < 1048576 (float4 count)
    float4 v = ((const float4*)x)[i];
    u16 h0 = f2bf(v.x), h1 = f2bf(v.y), h2 = f2bf(v.z), h3 = f2bf(v.w);
    ushort4 h, l;
    h.x = h0; h.y = h1; h.z = h2; h.w = h3;
    l.x = f2bf(v.x - bf2f(h0)); l.y = f2bf(v.y - bf2f(h1));
    l.z = f2bf(v.z - bf2f(h2)); l.w = f2bf(v.w - bf2f(h3));
    ((ushort4*)hi)[i] = h; ((ushort4*)lo)[i] = l;
}

// transpose + split the 4 weight matrices into [N][K] layout
__global__ __launch_bounds__(256) void split_wT_kernel(
    const float* __restrict__ Wq1, const float* __restrict__ Wk1,
    const float* __restrict__ Wq2, const float* __restrict__ Wk2,
    u16* __restrict__ w1hi, u16* __restrict__ w1lo,
    u16* __restrict__ w2hi, u16* __restrict__ w2lo) {
    int y = blockIdx.y;
    const float* src = (y == 0) ? Wq1 : (y == 1) ? Wk1 : (y == 2) ? Wq2 : Wk2;
    int R = (y < 2) ? 256 : 512;   // src rows = K of GEMM
    int C = (y < 2) ? 512 : 256;   // src cols = N of GEMM
    u16* dh = ((y < 2) ? w1hi : w2hi) + (y & 1) * 131072;
    u16* dl = ((y < 2) ? w1lo : w2lo) + (y & 1) * 131072;
    int i = blockIdx.x * 256 + threadIdx.x;       // < 131072
    int c = i / R, r = i - c * R;                 // out[c][r] = src[r][c]
    float v = src[(size_t)r * C + c];
    u16 h = f2bf(v);
    dh[i] = h; dl[i] = f2bf(v - bf2f(h));
}

__global__ void pack_bias(const float* __restrict__ bq1, const float* __restrict__ bk1,
                          const float* __restrict__ bq2, const float* __restrict__ bk2,
                          float* __restrict__ b1, float* __restrict__ b2) {
    int t = threadIdx.x;                           // 512 threads
    b1[t] = bq1[t]; b1[512 + t] = bk1[t];
    if (t < 256) { b2[t] = bq2[t]; b2[256 + t] = bk2[t]; }
}

// ---------------- split-bf16 GEMM: C[M,N] = A[M,K] * B[N,K]^T ----------------
// A always (hi,lo). SPLITB: B also (hi,lo) -> 3 MFMAs (hh+hl+lh). else 2 (hh+lh).
// SPLIT_OUT: bias+optional relu, write (hi,lo) bf16. F16S: write raw fp16 C.
// else raw fp32 C.
// Epilogue for bf16/fp16 outputs goes through an LDS transpose so global
// stores are 16B/lane coalesced (scalar 2B stores were ~4x slower).
#define BM 128
#define BN 128
#define BK 64

template<int SPLIT_OUT, int RELU, int SPLITB, int F16S>
__global__ __launch_bounds__(256, 2)
void gemm_bt(const u16* __restrict__ Ahi, const u16* __restrict__ Alo,
             const u16* __restrict__ Bhi, const u16* __restrict__ Blo,
             const float* __restrict__ bias, long biasBatch,
             void* __restrict__ Cout, u16* __restrict__ Chi, u16* __restrict__ Clo,
             int M, int N, int K,
             long aBatch, long bBatch, long cBatch) {
    __shared__ u16 lds[(3 + SPLITB) * BM * BK];   // Ahi | Alo | Bhi | [Blo], 16KB each
    const int tid = threadIdx.x;
    const int wave = tid >> 6, lane = tid & 63;

    // bijective XCD-aware block swizzle (T1/m204): consecutive tiles -> same XCD
    u32 gx = gridDim.x, gy = gridDim.y, gz = gridDim.z;
    u32 flat = (blockIdx.z * gy + blockIdx.y) * gx + blockIdx.x;
    u32 nwg = gx * gy * gz;
    u32 bx, by, bz;
    if ((nwg & 7u) == 0u) {
        u32 cpx = nwg >> 3;
        u32 nf = (flat & 7u) * cpx + (flat >> 3);
        bx = nf % gx; u32 t = nf / gx; by = t % gy; bz = t / gy;
    } else {
        bx = blockIdx.x; by = blockIdx.y; bz = blockIdx.z;
    }

    const long m0 = (long)by * BM, n0 = (long)bx * BN;

    const u16* pAhi = Ahi + (size_t)bz * aBatch;
    const u16* pAlo = Alo + (size_t)bz * aBatch;
    const u16* pBhi = Bhi + (size_t)bz * bBatch;
    const u16* pBlo = Blo + (size_t)bz * bBatch;

    // staging geometry: tile is [128 rows][64 k] bf16 = 16KB, linear.
    int srow[4], scol[4];
#pragma unroll
    for (int i = 0; i < 4; i++) {
        int lin = wave * 4096 + i * 1024 + lane * 16;  // byte offset in tile
        srow[i] = lin >> 7;            // row 0..127
        scol[i] = (lin & 127) >> 1;    // u16 index 0..63 within row
    }

    const int wr = wave >> 1, wc = wave & 1;
    const int lrow = lane & 15, kgrp = lane >> 4;

    f32x4 acc[4][4] = {};

    const int ksteps = K / BK;
    for (int kt = 0; kt < ksteps; ++kt) {
#pragma unroll
        for (int i = 0; i < 4; i++) {
            size_t ga = (size_t)(m0 + srow[i]) * K + (size_t)kt * BK + scol[i];
            size_t gb = (size_t)(n0 + srow[i]) * K + (size_t)kt * BK + scol[i];
            u32 lb = (u32)(wave * 4096 + i * 1024);    // wave-uniform LDS byte base
            gll16(pAhi + ga, (char*)lds + 0 * 16384 + lb);
            gll16(pAlo + ga, (char*)lds + 1 * 16384 + lb);
            gll16(pBhi + gb, (char*)lds + 2 * 16384 + lb);
            if constexpr (SPLITB) gll16(pBlo + gb, (char*)lds + 3 * 16384 + lb);
        }
        __syncthreads();
#pragma unroll
        for (int kk = 0; kk < 2; ++kk) {
            s16x8 ah[4], al[4], bh[4], bl[4];
            const int ko = kk * 32 + kgrp * 8;
#pragma unroll
            for (int m = 0; m < 4; m++) {
                int r = wr * 64 + m * 16 + lrow;
                ah[m] = *(const s16x8*)&lds[0 * 8192 + r * 64 + ko];
                al[m] = *(const s16x8*)&lds[1 * 8192 + r * 64 + ko];
            }
#pragma unroll
            for (int n = 0; n < 4; n++) {
                int r = wc * 64 + n * 16 + lrow;
                bh[n] = *(const s16x8*)&lds[2 * 8192 + r * 64 + ko];
                if constexpr (SPLITB) bl[n] = *(const s16x8*)&lds[3 * 8192 + r * 64 + ko];
            }
#pragma unroll
            for (int m = 0; m < 4; m++)
#pragma unroll
                for (int n = 0; n < 4; n++) {
                    acc[m][n] = __builtin_amdgcn_mfma_f32_16x16x32_bf16(ah[m], bh[n], acc[m][n], 0, 0, 0);
                    if constexpr (SPLITB)
                        acc[m][n] = __builtin_amdgcn_mfma_f32_16x16x32_bf16(ah[m], bl[n], acc[m][n], 0, 0, 0);
                    acc[m][n] = __builtin_amdgcn_mfma_f32_16x16x32_bf16(al[m], bh[n], acc[m][n], 0, 0, 0);
                }
        }
        __syncthreads();
    }

    // ---- epilogue ----
    // C/D fragment layout: col=lane&15, row=(lane>>4)*4+j  [guide §3, m89-verified]
    if constexpr (SPLIT_OUT || F16S) {
        // scatter acc -> LDS [128][128] u16 with XOR swizzle so the 4 kgrp
        // row-groups (rows r,r+4,r+8,r+12; 1024B apart = same banks) land on
        // disjoint 8-bank sets: col ^ (((row>>2)&3)<<4)  (+16 u16 = 8 banks).
        u16* sh  = (u16*)lds;            // hi (or f16) matrix, 32KB
        u16* slo = (u16*)lds + 16384;    // lo matrix (SPLIT_OUT only), 32KB
#pragma unroll
        for (int m = 0; m < 4; m++) {
#pragma unroll
            for (int n = 0; n < 4; n++) {
                int col_l = wc * 64 + n * 16 + lrow;
                float bv = 0.f;
                if constexpr (SPLIT_OUT) bv = bias[bz * biasBatch + n0 + col_l];
#pragma unroll
                for (int j = 0; j < 4; j++) {
                    int row_l = wr * 64 + m * 16 + kgrp * 4 + j;
                    int sc = col_l ^ (((row_l >> 2) & 3) << 4);
                    float v = acc[m][n][j];
                    if constexpr (SPLIT_OUT) {
                        v += bv;
                        if (RELU) v = fmaxf(v, 0.f);
                        u16 h = f2bf(v);
                        sh[row_l * 128 + sc]  = h;
                        slo[row_l * 128 + sc] = f2bf(v - bf2f(h));
                    } else {
                        union { f16 f; u16 u; } cv; cv.f = (f16)v;
                        sh[row_l * 128 + sc] = cv.u;
                    }
                }
            }
        }
        __syncthreads();
        // gather: 2048 16B chunks / matrix, 8 per thread, fully coalesced stores
#pragma unroll
        for (int i = 0; i < 8; i++) {
            int idx = i * 256 + tid;
            int row_l = idx >> 4;            // 0..127
            int c8 = (idx & 15) << 3;        // col start (multiple of 8)
            int sc = c8 ^ (((row_l >> 2) & 3) << 4);
            size_t go = (size_t)bz * cBatch + (size_t)(m0 + row_l) * N + n0 + c8;
            s16x8 vh = *(const s16x8*)&sh[row_l * 128 + sc];
            if constexpr (SPLIT_OUT) {
                s16x8 vl = *(const s16x8*)&slo[row_l * 128 + sc];
                *(s16x8*)&Chi[go] = vh;
                *(s16x8*)&Clo[go] = vl;
            } else {
                *(s16x8*)&((u16*)Cout)[go] = vh;
            }
        }
    } else {
        // raw fp32 path (fallback only)
#pragma unroll
        for (int m = 0; m < 4; m++)
#pragma unroll
            for (int n = 0; n < 4; n++) {
                long col = n0 + wc * 64 + n * 16 + lrow;
#pragma unroll
                for (int j = 0; j < 4; j++) {
                    long row = m0 + wr * 64 + m * 16 + kgrp * 4 + j;
                    ((float*)Cout)[(size_t)bz * cBatch + (size_t)row * N + col] = acc[m][n][j];
                }
            }
    }
}

// ---------------- softmax: dist = softmax(10*S/rowmax) ----------------
// fp32 in-place variant
__global__ __launch_bounds__(256) void softmax_rows(float* __restrict__ S) {
    const int tid = threadIdx.x;
    float* p = S + (size_t)blockIdx.x * 4096;
    float4 v[4];
    float lmax = -3.4e38f;
#pragma unroll
    for (int i = 0; i < 4; i++) {
        v[i] = ((float4*)p)[tid + 256 * i];
        lmax = fmaxf(lmax, fmaxf(fmaxf(v[i].x, v[i].y), fmaxf(v[i].z, v[i].w)));
    }
#pragma unroll
    for (int o = 32; o; o >>= 1) lmax = fmaxf(lmax, __shfl_xor(lmax, o));
    __shared__ float redm[4];
    __shared__ float reds[4];
    if ((tid & 63) == 0) redm[tid >> 6] = lmax;
    __syncthreads();
    const float m = fmaxf(fmaxf(redm[0], redm[1]), fmaxf(redm[2], redm[3]));
    const float c = 10.0f / m;
    float s = 0.f;
#pragma unroll
    for (int i = 0; i < 4; i++) {
        v[i].x = expf(c * v[i].x - 10.0f);
        v[i].y = expf(c * v[i].y - 10.0f);
        v[i].z = expf(c * v[i].z - 10.0f);
        v[i].w = expf(c * v[i].w - 10.0f);
        s += v[i].x + v[i].y + v[i].z + v[i].w;
    }
#pragma unroll
    for (int o = 32; o; o >>= 1) s += __shfl_xor(s, o);
    if ((tid & 63) == 0) reds[tid >> 6] = s;
    __syncthreads();
    const float inv = 1.0f / (reds[0] + reds[1] + reds[2] + reds[3]);
#pragma unroll
    for (int i = 0; i < 4; i++) {
        v[i].x *= inv; v[i].y *= inv; v[i].z *= inv; v[i].w *= inv;
        ((float4*)p)[tid + 256 * i] = v[i];
    }
}

// fp16-S variant: read fp16 S from ws, write fp32 dist to d_out
__global__ __launch_bounds__(256) void softmax_f16(const f16* __restrict__ S,
                                                   float* __restrict__ O) {
    const int tid = threadIdx.x;
    const f16* p = S + (size_t)blockIdx.x * 4096;
    float* o = O + (size_t)blockIdx.x * 4096;
    f16x8 a0 = ((const f16x8*)p)[tid];          // elements 8*tid ..
    f16x8 a1 = ((const f16x8*)p)[tid + 256];    // elements 8*(tid+256) ..
    float v[16];
#pragma unroll
    for (int j = 0; j < 8; j++) { v[j] = (float)a0[j]; v[8 + j] = (float)a1[j]; }
    float lmax = -3.4e38f;
#pragma unroll
    for (int j = 0; j < 16; j++) lmax = fmaxf(lmax, v[j]);
#pragma unroll
    for (int off = 32; off; off >>= 1) lmax = fmaxf(lmax, __shfl_xor(lmax, off));
    __shared__ float redm[4];
    __shared__ float reds[4];
    if ((tid & 63) == 0) redm[tid >> 6] = lmax;
    __syncthreads();
    const float m = fmaxf(fmaxf(redm[0], redm[1]), fmaxf(redm[2], redm[3]));
    const float c = 10.0f / m;
    float s = 0.f;
#pragma unroll
    for (int j = 0; j < 16; j++) { v[j] = expf(c * v[j] - 10.0f); s += v[j]; }
#pragma unroll
    for (int off = 32; off; off >>= 1) s += __shfl_xor(s, off);
    if ((tid & 63) == 0) reds[tid >> 6] = s;
    __syncthreads();
    const float inv = 1.0f / (reds[0] + reds[1] + reds[2] + reds[3]);
    float4 w;
#pragma unroll
    for (int q = 0; q < 4; q++) {
        int base = q * 4;
        w.x = v[base + 0] * inv; w.y = v[base + 1] * inv;
        w.z = v[base + 2] * inv; w.w = v[base + 3] * inv;
        int idx = (q < 2) ? (2 * tid + q) : (2 * tid + 512 + (q - 2));
        ((float4*)o)[idx] = w;
    }
}

// ---------------- launch ----------------
extern "C" void kernel_launch(void* const* d_in, const int* in_sizes, int n_in,
                              void* d_out, int out_size, void* d_ws, size_t ws_size,
                              hipStream_t stream) {
    const float* x   = (const float*)d_in[0];
    const float* Wq1 = (const float*)d_in[1];
    const float* bq1 = (const float*)d_in[2];
    const float* Wq2 = (const float*)d_in[3];
    const float* bq2 = (const float*)d_in[4];
    const float* Wk1 = (const float*)d_in[5];
    const float* bk1 = (const float*)d_in[6];
    const float* Wk2 = (const float*)d_in[7];
    const float* bk2 = (const float*)d_in[8];
    float* out = (float*)d_out;

    const size_t MB = 1048576;
    char* ws = (char*)d_ws;
    // ws layout: biases | weights | Q/K splits | [S fp16]
    float* b1 = (float*)(ws);                    // 4KB
    float* b2 = (float*)(ws + 4096);             // 2KB (reserve to 8KB)
    u16* w1hi = (u16*)(ws + 8 * 1024);           // 512KB
    u16* w1lo = (u16*)(ws + 8 * 1024 + 512 * 1024);
    u16* w2hi = (u16*)(ws + 8 * 1024 + 1024 * 1024);
    u16* w2lo = (u16*)(ws + 8 * 1024 + 1536 * 1024);
    u16* qhi  = (u16*)(ws + 4 * MB);             // 8MB
    u16* khi  = (u16*)(ws + 12 * MB);            // 8MB
    u16* qlo  = (u16*)(ws + 20 * MB);            // 8MB
    u16* klo  = (u16*)(ws + 28 * MB);            // 8MB (written, unused by QK^T)
    f16* S16  = (f16*)(ws + 36 * MB);            // 128MB if available

    const bool f16s = (ws_size >= 164 * MB);

    // d_out doubles as scratch before QK^T/softmax overwrites it:
    char* ob = (char*)d_out;
    u16* xhi = (u16*)(ob + 0 * MB);    // 8MB
    u16* xlo = (u16*)(ob + 8 * MB);    // 8MB
    u16* Hhi = (u16*)(ob + 16 * MB);   // [2][16384][512] = 32MB
    u16* Hlo = (u16*)(ob + 48 * MB);   // 32MB

    split_x_kernel<<<4096, 256, 0, stream>>>(x, xhi, xlo);
    split_wT_kernel<<<dim3(512, 4), 256, 0, stream>>>(Wq1, Wk1, Wq2, Wk2,
                                                      w1hi, w1lo, w2hi, w2lo);
    pack_bias<<<1, 512, 0, stream>>>(bq1, bk1, bq2, bk2, b1, b2);

    // layer 1 (both branches): H = relu(x*W1 + b1)  [16384,512], split output
    gemm_bt<1, 1, 1, 0><<<dim3(4, 128, 2), 256, 0, stream>>>(
        xhi, xlo, w1hi, w1lo, b1, 512,
        nullptr, Hhi, Hlo,
        16384, 512, 256,
        0L, 131072L, 8388608L);

    // layer 2 (both branches): Q/K = H*W2 + b2  [16384,256], split output into ws
    gemm_bt<1, 0, 1, 0><<<dim3(2, 128, 2), 256, 0, stream>>>(
        Hhi, Hlo, w2hi, w2lo, b2, 256,
        nullptr, qhi, qlo,
        16384, 256, 512,
        8388608L, 131072L, 4194304L);

    // S = Q*K^T per batch: A split, B = khi only (2-MFMA)
    if (f16s) {
        gemm_bt<0, 0, 0, 1><<<dim3(32, 32, 4), 256, 0, stream>>>(
            qhi, qlo, khi, klo, nullptr, 0,
            (void*)S16, nullptr, nullptr,
            4096, 4096, 256,
            1048576L, 1048576L, 16777216L);
        softmax_f16<<<16384, 256, 0, stream>>>(S16, out);
    } else {
        gemm_bt<0, 0, 0, 0><<<dim3(32, 32, 4), 256, 0, stream>>>(
            qhi, qlo, khi, klo, nullptr, 0,
            (void*)out, nullptr, nullptr,
            4096, 4096, 256,
            1048576L, 1048576L, 16777216L);
        softmax_rows<<<16384, 256, 0, stream>>>(out);
    }
}

// Round 8
// 460.527 us; speedup vs baseline: 1.1608x; 1.0178x over previous
//
#include <hip/hip_runtime.h>
#include <hip/hip_bf16.h>

typedef unsigned short u16;
typedef unsigned int u32;
typedef _Float16 f16;
typedef __attribute__((ext_vector_type(4))) float f32x4;
typedef __attribute__((ext_vector_type(8))) short s16x8;
typedef __attribute__((ext_vector_type(8))) _Float16 f16x8;

__device__ __forceinline__ u16 f2bf(float f) {
    union { float f; u32 u; } v; v.f = f;
    u32 r = v.u + 0x7FFFu + ((v.u >> 16) & 1u);
    return (u16)(r >> 16);
}
__device__ __forceinline__ float bf2f(u16 h) {
    union { u32 u; float f; } v; v.u = ((u32)h) << 16;
    return v.f;
}

__device__ __forceinline__ void gll16(const void* g, void* l) {
    __builtin_amdgcn_global_load_lds(
        (const __attribute__((address_space(1))) void*)g,
        (__attribute__((address_space(3))) void*)l, 16, 0, 0);
}

// ---------------- prep kernels ----------------

__global__ __launch_bounds__(256) void split_x_kernel(
    const float* __restrict__ x, u16* __restrict__ hi, u16* __restrict__ lo) {
    int i = blockIdx.x * 256 + threadIdx.x;       // < 1048576 (float4 count)
    float4 v = ((const float4*)x)[i];
    u16 h0 = f2bf(v.x), h1 = f2bf(v.y), h2 = f2bf(v.z), h3 = f2bf(v.w);
    ushort4 h, l;
    h.x = h0; h.y = h1; h.z = h2; h.w = h3;
    l.x = f2bf(v.x - bf2f(h0)); l.y = f2bf(v.y - bf2f(h1));
    l.z = f2bf(v.z - bf2f(h2)); l.w = f2bf(v.w - bf2f(h3));
    ((ushort4*)hi)[i] = h; ((ushort4*)lo)[i] = l;
}

// transpose + split the 4 weight matrices into [N][K] layout
__global__ __launch_bounds__(256) void split_wT_kernel(
    const float* __restrict__ Wq1, const float* __restrict__ Wk1,
    const float* __restrict__ Wq2, const float* __restrict__ Wk2,
    u16* __restrict__ w1hi, u16* __restrict__ w1lo,
    u16* __restrict__ w2hi, u16* __restrict__ w2lo) {
    int y = blockIdx.y;
    const float* src = (y == 0) ? Wq1 : (y == 1) ? Wk1 : (y == 2) ? Wq2 : Wk2;
    int R = (y < 2) ? 256 : 512;   // src rows = K of GEMM
    int C = (y < 2) ? 512 : 256;   // src cols = N of GEMM
    u16* dh = ((y < 2) ? w1hi : w2hi) + (y & 1) * 131072;
    u16* dl = ((y < 2) ? w1lo : w2lo) + (y & 1) * 131072;
    int i = blockIdx.x * 256 + threadIdx.x;       // < 131072
    int c = i / R, r = i - c * R;                 // out[c][r] = src[r][c]
    float v = src[(size_t)r * C + c];
    u16 h = f2bf(v);
    dh[i] = h; dl[i] = f2bf(v - bf2f(h));
}

__global__ void pack_bias(const float* __restrict__ bq1, const float* __restrict__ bk1,
                          const float* __restrict__ bq2, const float* __restrict__ bk2,
                          float* __restrict__ b1, float* __restrict__ b2) {
    int t = threadIdx.x;                           // 512 threads
    b1[t] = bq1[t]; b1[512 + t] = bk1[t];
    if (t < 256) { b2[t] = bq2[t]; b2[256 + t] = bk2[t]; }
}

// ---------------- split-bf16 GEMM: C[M,N] = A[M,K] * B[N,K]^T ----------------
// A always (hi,lo). SPLITB: B also (hi,lo) -> 3 MFMAs (hh+hl+lh). else 2 (hh+lh).
// SPLIT_OUT: bias+optional relu, write (hi,lo) bf16. F16S: write raw fp16 C.
// K-loop is 2-phase software-pipelined (T3-min): double-buffered LDS, BK=32,
// next tile's global_load_lds issued BEFORE compute of current tile, ONE
// barrier per K-step (vmcnt drain overlaps ~48 MFMAs of compute).
#define BM 128
#define BN 128
#define BKT 32

template<int SPLIT_OUT, int RELU, int SPLITB, int F16S>
__global__ __launch_bounds__(256, 2)
void gemm_bt(const u16* __restrict__ Ahi, const u16* __restrict__ Alo,
             const u16* __restrict__ Bhi, const u16* __restrict__ Blo,
             const float* __restrict__ bias, long biasBatch,
             void* __restrict__ Cout, u16* __restrict__ Chi, u16* __restrict__ Clo,
             int M, int N, int K,
             long aBatch, long bBatch, long cBatch) {
    constexpr int NMAT  = 3 + SPLITB;        // Ahi|Alo|Bhi|[Blo]
    constexpr int TILEU = BM * BKT;          // 4096 u16 = 8KB per matrix-tile
    constexpr int HALFU = NMAT * TILEU;      // u16 per buffer
    __shared__ u16 lds[2 * HALFU];           // 48KB (QKT) / 64KB (MLP)

    const int tid = threadIdx.x;
    const int wave = tid >> 6, lane = tid & 63;

    // bijective XCD-aware block swizzle (T1/m204)
    u32 gx = gridDim.x, gy = gridDim.y, gz = gridDim.z;
    u32 flat = (blockIdx.z * gy + blockIdx.y) * gx + blockIdx.x;
    u32 nwg = gx * gy * gz;
    u32 bx, by, bz;
    if ((nwg & 7u) == 0u) {
        u32 cpx = nwg >> 3;
        u32 nf = (flat & 7u) * cpx + (flat >> 3);
        bx = nf % gx; u32 t = nf / gx; by = t % gy; bz = t / gy;
    } else {
        bx = blockIdx.x; by = blockIdx.y; bz = blockIdx.z;
    }

    const long m0 = (long)by * BM, n0 = (long)bx * BN;

    const u16* pAhi = Ahi + (size_t)bz * aBatch;
    const u16* pAlo = Alo + (size_t)bz * aBatch;
    const u16* pBhi = Bhi + (size_t)bz * bBatch;
    const u16* pBlo = Blo + (size_t)bz * bBatch;

    // staging geometry: tile is [128 rows][32 k] u16 = 8KB, linear.
    // per thread: 2 chunks of 16B per matrix. lin = i*4096 + tid*16 bytes.
    int srow[2], scol[2];
#pragma unroll
    for (int i = 0; i < 2; i++) {
        int lin = i * 4096 + tid * 16;
        srow[i] = lin >> 6;            // row 0..127 (64B per row)
        scol[i] = (lin & 63) >> 1;     // u16 index 0..31 within row
    }

    const int wr = wave >> 1, wc = wave & 1;
    const int lrow = lane & 15, kgrp = lane >> 4;
    const int ko = kgrp * 8;

    f32x4 acc[4][4] = {};

    auto stage = [&](int b, int kt) {
#pragma unroll
        for (int i = 0; i < 2; i++) {
            size_t ga = (size_t)(m0 + srow[i]) * K + (size_t)kt * BKT + scol[i];
            size_t gb = (size_t)(n0 + srow[i]) * K + (size_t)kt * BKT + scol[i];
            u32 lb = (u32)(b * (HALFU * 2) + i * 4096 + wave * 1024); // bytes, wave-uniform
            gll16(pAhi + ga, (char*)lds + 0 * 8192 + lb);
            gll16(pAlo + ga, (char*)lds + 1 * 8192 + lb);
            gll16(pBhi + gb, (char*)lds + 2 * 8192 + lb);
            if constexpr (SPLITB) gll16(pBlo + gb, (char*)lds + 3 * 8192 + lb);
        }
    };

    auto compute = [&](int b) {
        const u16* B0 = lds + b * HALFU;
        s16x8 ah[4], al[4], bh[4], bl[4];
#pragma unroll
        for (int m = 0; m < 4; m++) {
            int r = wr * 64 + m * 16 + lrow;
            ah[m] = *(const s16x8*)&B0[0 * TILEU + r * 32 + ko];
            al[m] = *(const s16x8*)&B0[1 * TILEU + r * 32 + ko];
        }
#pragma unroll
        for (int n = 0; n < 4; n++) {
            int r = wc * 64 + n * 16 + lrow;
            bh[n] = *(const s16x8*)&B0[2 * TILEU + r * 32 + ko];
            if constexpr (SPLITB) bl[n] = *(const s16x8*)&B0[3 * TILEU + r * 32 + ko];
        }
#pragma unroll
        for (int m = 0; m < 4; m++)
#pragma unroll
            for (int n = 0; n < 4; n++) {
                acc[m][n] = __builtin_amdgcn_mfma_f32_16x16x32_bf16(ah[m], bh[n], acc[m][n], 0, 0, 0);
                if constexpr (SPLITB)
                    acc[m][n] = __builtin_amdgcn_mfma_f32_16x16x32_bf16(ah[m], bl[n], acc[m][n], 0, 0, 0);
                acc[m][n] = __builtin_amdgcn_mfma_f32_16x16x32_bf16(al[m], bh[n], acc[m][n], 0, 0, 0);
            }
    };

    const int ksteps = K / BKT;      // 8 or 16
    // prologue
    stage(0, 0);
    __syncthreads();                  // drains prologue loads
    int cur = 0;
    for (int kt = 0; kt < ksteps - 1; ++kt) {
        stage(cur ^ 1, kt + 1);       // issue next tile FIRST (overlaps compute)
        compute(cur);
        __syncthreads();              // one barrier/step: drains stage(cur^1),
        cur ^= 1;                     // and fences readers of buf cur
    }
    compute(cur);
    __syncthreads();                  // all reads done before epilogue reuses LDS

    // ---- epilogue ----
    // C/D fragment layout: col=lane&15, row=(lane>>4)*4+j  [guide §3, m89-verified]
    if constexpr (SPLIT_OUT || F16S) {
        // scatter acc -> LDS [128][128] u16 with XOR swizzle (bank-spread),
        // then gather 16B/lane coalesced stores.
        u16* sh  = (u16*)lds;            // 32KB
        u16* slo = (u16*)lds + 16384;    // 32KB (SPLIT_OUT only)
#pragma unroll
        for (int m = 0; m < 4; m++) {
#pragma unroll
            for (int n = 0; n < 4; n++) {
                int col_l = wc * 64 + n * 16 + lrow;
                float bv = 0.f;
                if constexpr (SPLIT_OUT) bv = bias[bz * biasBatch + n0 + col_l];
#pragma unroll
                for (int j = 0; j < 4; j++) {
                    int row_l = wr * 64 + m * 16 + kgrp * 4 + j;
                    int sc = col_l ^ (((row_l >> 2) & 3) << 4);
                    float v = acc[m][n][j];
                    if constexpr (SPLIT_OUT) {
                        v += bv;
                        if (RELU) v = fmaxf(v, 0.f);
                        u16 h = f2bf(v);
                        sh[row_l * 128 + sc]  = h;
                        slo[row_l * 128 + sc] = f2bf(v - bf2f(h));
                    } else {
                        union { f16 f; u16 u; } cv; cv.f = (f16)v;
                        sh[row_l * 128 + sc] = cv.u;
                    }
                }
            }
        }
        __syncthreads();
#pragma unroll
        for (int i = 0; i < 8; i++) {
            int idx = i * 256 + tid;
            int row_l = idx >> 4;            // 0..127
            int c8 = (idx & 15) << 3;        // col start (multiple of 8)
            int sc = c8 ^ (((row_l >> 2) & 3) << 4);
            size_t go = (size_t)bz * cBatch + (size_t)(m0 + row_l) * N + n0 + c8;
            s16x8 vh = *(const s16x8*)&sh[row_l * 128 + sc];
            if constexpr (SPLIT_OUT) {
                s16x8 vl = *(const s16x8*)&slo[row_l * 128 + sc];
                *(s16x8*)&Chi[go] = vh;
                *(s16x8*)&Clo[go] = vl;
            } else {
                *(s16x8*)&((u16*)Cout)[go] = vh;
            }
        }
    } else {
        // raw fp32 path (fallback only)
#pragma unroll
        for (int m = 0; m < 4; m++)
#pragma unroll
            for (int n = 0; n < 4; n++) {
                long col = n0 + wc * 64 + n * 16 + lrow;
#pragma unroll
                for (int j = 0; j < 4; j++) {
                    long row = m0 + wr * 64 + m * 16 + kgrp * 4 + j;
                    ((float*)Cout)[(size_t)bz * cBatch + (size_t)row * N + col] = acc[m][n][j];
                }
            }
    }
}

// ---------------- softmax: dist = softmax(10*S/rowmax) ----------------
// fp32 in-place variant
__global__ __launch_bounds__(256) void softmax_rows(float* __restrict__ S) {
    const int tid = threadIdx.x;
    float* p = S + (size_t)blockIdx.x * 4096;
    float4 v[4];
    float lmax = -3.4e38f;
#pragma unroll
    for (int i = 0; i < 4; i++) {
        v[i] = ((float4*)p)[tid + 256 * i];
        lmax = fmaxf(lmax, fmaxf(fmaxf(v[i].x, v[i].y), fmaxf(v[i].z, v[i].w)));
    }
#pragma unroll
    for (int o = 32; o; o >>= 1) lmax = fmaxf(lmax, __shfl_xor(lmax, o));
    __shared__ float redm[4];
    __shared__ float reds[4];
    if ((tid & 63) == 0) redm[tid >> 6] = lmax;
    __syncthreads();
    const float m = fmaxf(fmaxf(redm[0], redm[1]), fmaxf(redm[2], redm[3]));
    const float c = 10.0f / m;
    float s = 0.f;
#pragma unroll
    for (int i = 0; i < 4; i++) {
        v[i].x = expf(c * v[i].x - 10.0f);
        v[i].y = expf(c * v[i].y - 10.0f);
        v[i].z = expf(c * v[i].z - 10.0f);
        v[i].w = expf(c * v[i].w - 10.0f);
        s += v[i].x + v[i].y + v[i].z + v[i].w;
    }
#pragma unroll
    for (int o = 32; o; o >>= 1) s += __shfl_xor(s, o);
    if ((tid & 63) == 0) reds[tid >> 6] = s;
    __syncthreads();
    const float inv = 1.0f / (reds[0] + reds[1] + reds[2] + reds[3]);
#pragma unroll
    for (int i = 0; i < 4; i++) {
        v[i].x *= inv; v[i].y *= inv; v[i].z *= inv; v[i].w *= inv;
        ((float4*)p)[tid + 256 * i] = v[i];
    }
}

// fp16-S variant: read fp16 S from ws, write fp32 dist to d_out
__global__ __launch_bounds__(256) void softmax_f16(const f16* __restrict__ S,
                                                   float* __restrict__ O) {
    const int tid = threadIdx.x;
    const f16* p = S + (size_t)blockIdx.x * 4096;
    float* o = O + (size_t)blockIdx.x * 4096;
    f16x8 a0 = ((const f16x8*)p)[tid];          // elements 8*tid ..
    f16x8 a1 = ((const f16x8*)p)[tid + 256];    // elements 8*(tid+256) ..
    float v[16];
#pragma unroll
    for (int j = 0; j < 8; j++) { v[j] = (float)a0[j]; v[8 + j] = (float)a1[j]; }
    float lmax = -3.4e38f;
#pragma unroll
    for (int j = 0; j < 16; j++) lmax = fmaxf(lmax, v[j]);
#pragma unroll
    for (int off = 32; off; off >>= 1) lmax = fmaxf(lmax, __shfl_xor(lmax, off));
    __shared__ float redm[4];
    __shared__ float reds[4];
    if ((tid & 63) == 0) redm[tid >> 6] = lmax;
    __syncthreads();
    const float m = fmaxf(fmaxf(redm[0], redm[1]), fmaxf(redm[2], redm[3]));
    const float c = 10.0f / m;
    float s = 0.f;
#pragma unroll
    for (int j = 0; j < 16; j++) { v[j] = expf(c * v[j] - 10.0f); s += v[j]; }
#pragma unroll
    for (int off = 32; off; off >>= 1) s += __shfl_xor(s, off);
    if ((tid & 63) == 0) reds[tid >> 6] = s;
    __syncthreads();
    const float inv = 1.0f / (reds[0] + reds[1] + reds[2] + reds[3]);
    float4 w;
#pragma unroll
    for (int q = 0; q < 4; q++) {
        int base = q * 4;
        w.x = v[base + 0] * inv; w.y = v[base + 1] * inv;
        w.z = v[base + 2] * inv; w.w = v[base + 3] * inv;
        int idx = (q < 2) ? (2 * tid + q) : (2 * tid + 512 + (q - 2));
        ((float4*)o)[idx] = w;
    }
}

// ---------------- launch ----------------
extern "C" void kernel_launch(void* const* d_in, const int* in_sizes, int n_in,
                              void* d_out, int out_size, void* d_ws, size_t ws_size,
                              hipStream_t stream) {
    const float* x   = (const float*)d_in[0];
    const float* Wq1 = (const float*)d_in[1];
    const float* bq1 = (const float*)d_in[2];
    const float* Wq2 = (const float*)d_in[3];
    const float* bq2 = (const float*)d_in[4];
    const float* Wk1 = (const float*)d_in[5];
    const float* bk1 = (const float*)d_in[6];
    const float* Wk2 = (const float*)d_in[7];
    const float* bk2 = (const float*)d_in[8];
    float* out = (float*)d_out;

    const size_t MB = 1048576;
    char* ws = (char*)d_ws;
    // ws layout: biases | weights | Q/K splits | [S fp16]
    float* b1 = (float*)(ws);                    // 4KB
    float* b2 = (float*)(ws + 4096);             // 2KB (reserve to 8KB)
    u16* w1hi = (u16*)(ws + 8 * 1024);           // 512KB
    u16* w1lo = (u16*)(ws + 8 * 1024 + 512 * 1024);
    u16* w2hi = (u16*)(ws + 8 * 1024 + 1024 * 1024);
    u16* w2lo = (u16*)(ws + 8 * 1024 + 1536 * 1024);
    u16* qhi  = (u16*)(ws + 4 * MB);             // 8MB
    u16* khi  = (u16*)(ws + 12 * MB);            // 8MB
    u16* qlo  = (u16*)(ws + 20 * MB);            // 8MB
    u16* klo  = (u16*)(ws + 28 * MB);            // 8MB (written, unused by QK^T)
    f16* S16  = (f16*)(ws + 36 * MB);            // 128MB if available

    const bool f16s = (ws_size >= 164 * MB);

    // d_out doubles as scratch before QK^T/softmax overwrites it:
    char* ob = (char*)d_out;
    u16* xhi = (u16*)(ob + 0 * MB);    // 8MB
    u16* xlo = (u16*)(ob + 8 * MB);    // 8MB
    u16* Hhi = (u16*)(ob + 16 * MB);   // [2][16384][512] = 32MB
    u16* Hlo = (u16*)(ob + 48 * MB);   // 32MB

    split_x_kernel<<<4096, 256, 0, stream>>>(x, xhi, xlo);
    split_wT_kernel<<<dim3(512, 4), 256, 0, stream>>>(Wq1, Wk1, Wq2, Wk2,
                                                      w1hi, w1lo, w2hi, w2lo);
    pack_bias<<<1, 512, 0, stream>>>(bq1, bk1, bq2, bk2, b1, b2);

    // layer 1 (both branches): H = relu(x*W1 + b1)  [16384,512], split output
    gemm_bt<1, 1, 1, 0><<<dim3(4, 128, 2), 256, 0, stream>>>(
        xhi, xlo, w1hi, w1lo, b1, 512,
        nullptr, Hhi, Hlo,
        16384, 512, 256,
        0L, 131072L, 8388608L);

    // layer 2 (both branches): Q/K = H*W2 + b2  [16384,256], split output into ws
    gemm_bt<1, 0, 1, 0><<<dim3(2, 128, 2), 256, 0, stream>>>(
        Hhi, Hlo, w2hi, w2lo, b2, 256,
        nullptr, qhi, qlo,
        16384, 256, 512,
        8388608L, 131072L, 4194304L);

    // S = Q*K^T per batch: A split, B = khi only (2-MFMA)
    if (f16s) {
        gemm_bt<0, 0, 0, 1><<<dim3(32, 32, 4), 256, 0, stream>>>(
            qhi, qlo, khi, klo, nullptr, 0,
            (void*)S16, nullptr, nullptr,
            4096, 4096, 256,
            1048576L, 1048576L, 16777216L);
        softmax_f16<<<16384, 256, 0, stream>>>(S16, out);
    } else {
        gemm_bt<0, 0, 0, 0><<<dim3(32, 32, 4), 256, 0, stream>>>(
            qhi, qlo, khi, klo, nullptr, 0,
            (void*)out, nullptr, nullptr,
            4096, 4096, 256,
            1048576L, 1048576L, 16777216L);
        softmax_rows<<<16384, 256, 0, stream>>>(out);
    }
}

// Round 10
// 431.254 us; speedup vs baseline: 1.2396x; 1.0679x over previous
//
#include <hip/hip_runtime.h>
#include <hip/hip_bf16.h>

typedef unsigned short u16;
typedef unsigned int u32;
typedef _Float16 f16;
typedef __attribute__((ext_vector_type(4))) float f32x4;
typedef __attribute__((ext_vector_type(8))) short s16x8;
typedef __attribute__((ext_vector_type(8))) _Float16 f16x8;

__device__ __forceinline__ u16 f2bf(float f) {
    union { float f; u32 u; } v; v.f = f;
    u32 r = v.u + 0x7FFFu + ((v.u >> 16) & 1u);
    return (u16)(r >> 16);
}
__device__ __forceinline__ float bf2f(u16 h) {
    union { u32 u; float f; } v; v.u = ((u32)h) << 16;
    return v.f;
}

__device__ __forceinline__ void gll16(const void* g, void* l) {
    __builtin_amdgcn_global_load_lds(
        (const __attribute__((address_space(1))) void*)g,
        (__attribute__((address_space(3))) void*)l, 16, 0, 0);
}

// ---------------- prep kernels ----------------

__global__ __launch_bounds__(256) void split_x_kernel(
    const float* __restrict__ x, u16* __restrict__ hi, u16* __restrict__ lo) {
    int i = blockIdx.x * 256 + threadIdx.x;       // < 1048576 (float4 count)
    float4 v = ((const float4*)x)[i];
    u16 h0 = f2bf(v.x), h1 = f2bf(v.y), h2 = f2bf(v.z), h3 = f2bf(v.w);
    ushort4 h, l;
    h.x = h0; h.y = h1; h.z = h2; h.w = h3;
    l.x = f2bf(v.x - bf2f(h0)); l.y = f2bf(v.y - bf2f(h1));
    l.z = f2bf(v.z - bf2f(h2)); l.w = f2bf(v.w - bf2f(h3));
    ((ushort4*)hi)[i] = h; ((ushort4*)lo)[i] = l;
}

// transpose + split the 4 weight matrices into [N][K] layout
__global__ __launch_bounds__(256) void split_wT_kernel(
    const float* __restrict__ Wq1, const float* __restrict__ Wk1,
    const float* __restrict__ Wq2, const float* __restrict__ Wk2,
    u16* __restrict__ w1hi, u16* __restrict__ w1lo,
    u16* __restrict__ w2hi, u16* __restrict__ w2lo) {
    int y = blockIdx.y;
    const float* src = (y == 0) ? Wq1 : (y == 1) ? Wk1 : (y == 2) ? Wq2 : Wk2;
    int R = (y < 2) ? 256 : 512;   // src rows = K of GEMM
    int C = (y < 2) ? 512 : 256;   // src cols = N of GEMM
    u16* dh = ((y < 2) ? w1hi : w2hi) + (y & 1) * 131072;
    u16* dl = ((y < 2) ? w1lo : w2lo) + (y & 1) * 131072;
    int i = blockIdx.x * 256 + threadIdx.x;       // < 131072
    int c = i / R, r = i - c * R;                 // out[c][r] = src[r][c]
    float v = src[(size_t)r * C + c];
    u16 h = f2bf(v);
    dh[i] = h; dl[i] = f2bf(v - bf2f(h));
}

__global__ void pack_bias(const float* __restrict__ bq1, const float* __restrict__ bk1,
                          const float* __restrict__ bq2, const float* __restrict__ bk2,
                          float* __restrict__ b1, float* __restrict__ b2) {
    int t = threadIdx.x;                           // 512 threads
    b1[t] = bq1[t]; b1[512 + t] = bk1[t];
    if (t < 256) { b2[t] = bq2[t]; b2[256 + t] = bk2[t]; }
}

// ---------------- GEMM: C[M,N] = A[M,K] * B[N,K]^T ----------------
// F16AB=0: A,B split bf16 (hi,lo), 3 MFMAs (hh+hl+lh), fp32-grade.
// F16AB=1: A,B single fp16, 1 f16-MFMA (QK^T; quantization ~2.8e-4 rel).
// OUTMODE: 0 = (hi,lo) split bf16 pair; 1 = single fp16; 2 = raw fp32.
// BIAS/RELU applied before output conversion.
// 2-phase pipelined K-loop (dbuf LDS, BK=32, stage-next-then-compute).
#define BM 128
#define BN 128
#define BKT 32

template<int F16AB, int BIAS, int RELU, int OUTMODE>
__global__ __launch_bounds__(256, 2)
void gemm_bt(const u16* __restrict__ Ahi, const u16* __restrict__ Alo,
             const u16* __restrict__ Bhi, const u16* __restrict__ Blo,
             const float* __restrict__ bias, long biasBatch,
             u16* __restrict__ C1, u16* __restrict__ C2,
             int M, int N, int K,
             long aBatch, long bBatch, long cBatch) {
    constexpr int NMAT  = F16AB ? 2 : 4;     // [Ahi|Bhi] or [Ahi|Alo|Bhi|Blo]
    constexpr int TILEU = BM * BKT;          // 4096 u16 = 8KB per matrix-tile
    constexpr int HALFU = NMAT * TILEU;      // u16 per buffer
    __shared__ u16 lds[2 * HALFU];           // 32KB (f16) / 64KB (split)

    const int tid = threadIdx.x;
    const int wave = tid >> 6, lane = tid & 63;

    // bijective XCD-aware block swizzle (T1/m204)
    u32 gx = gridDim.x, gy = gridDim.y, gz = gridDim.z;
    u32 flat = (blockIdx.z * gy + blockIdx.y) * gx + blockIdx.x;
    u32 nwg = gx * gy * gz;
    u32 bx, by, bz;
    if ((nwg & 7u) == 0u) {
        u32 cpx = nwg >> 3;
        u32 nf = (flat & 7u) * cpx + (flat >> 3);
        bx = nf % gx; u32 t = nf / gx; by = t % gy; bz = t / gy;
    } else {
        bx = blockIdx.x; by = blockIdx.y; bz = blockIdx.z;
    }

    const long m0 = (long)by * BM, n0 = (long)bx * BN;

    const u16* pAhi = Ahi + (size_t)bz * aBatch;
    const u16* pAlo = Alo + (size_t)bz * aBatch;
    const u16* pBhi = Bhi + (size_t)bz * bBatch;
    const u16* pBlo = Blo + (size_t)bz * bBatch;

    // staging geometry: tile is [128 rows][32 k] u16 = 8KB, linear.
    int srow[2], scol[2];
#pragma unroll
    for (int i = 0; i < 2; i++) {
        int lin = i * 4096 + tid * 16;
        srow[i] = lin >> 6;            // row 0..127 (64B per row)
        scol[i] = (lin & 63) >> 1;     // u16 index 0..31 within row
    }

    const int wr = wave >> 1, wc = wave & 1;
    const int lrow = lane & 15, kgrp = lane >> 4;
    const int ko = kgrp * 8;

    f32x4 acc[4][4] = {};

    auto stage = [&](int b, int kt) {
#pragma unroll
        for (int i = 0; i < 2; i++) {
            size_t ga = (size_t)(m0 + srow[i]) * K + (size_t)kt * BKT + scol[i];
            size_t gb = (size_t)(n0 + srow[i]) * K + (size_t)kt * BKT + scol[i];
            u32 lb = (u32)(b * (HALFU * 2) + i * 4096 + wave * 1024); // bytes
            if constexpr (F16AB) {
                gll16(pAhi + ga, (char*)lds + 0 * 8192 + lb);
                gll16(pBhi + gb, (char*)lds + 1 * 8192 + lb);
            } else {
                gll16(pAhi + ga, (char*)lds + 0 * 8192 + lb);
                gll16(pAlo + ga, (char*)lds + 1 * 8192 + lb);
                gll16(pBhi + gb, (char*)lds + 2 * 8192 + lb);
                gll16(pBlo + gb, (char*)lds + 3 * 8192 + lb);
            }
        }
    };

    auto compute = [&](int b) {
        const u16* B0 = lds + b * HALFU;
        if constexpr (F16AB) {
            f16x8 a[4], bb[4];
#pragma unroll
            for (int m = 0; m < 4; m++) {
                int r = wr * 64 + m * 16 + lrow;
                a[m] = *(const f16x8*)&B0[0 * TILEU + r * 32 + ko];
            }
#pragma unroll
            for (int n = 0; n < 4; n++) {
                int r = wc * 64 + n * 16 + lrow;
                bb[n] = *(const f16x8*)&B0[1 * TILEU + r * 32 + ko];
            }
#pragma unroll
            for (int m = 0; m < 4; m++)
#pragma unroll
                for (int n = 0; n < 4; n++)
                    acc[m][n] = __builtin_amdgcn_mfma_f32_16x16x32_f16(a[m], bb[n], acc[m][n], 0, 0, 0);
        } else {
            s16x8 ah[4], al[4], bh[4], bl[4];
#pragma unroll
            for (int m = 0; m < 4; m++) {
                int r = wr * 64 + m * 16 + lrow;
                ah[m] = *(const s16x8*)&B0[0 * TILEU + r * 32 + ko];
                al[m] = *(const s16x8*)&B0[1 * TILEU + r * 32 + ko];
            }
#pragma unroll
            for (int n = 0; n < 4; n++) {
                int r = wc * 64 + n * 16 + lrow;
                bh[n] = *(const s16x8*)&B0[2 * TILEU + r * 32 + ko];
                bl[n] = *(const s16x8*)&B0[3 * TILEU + r * 32 + ko];
            }
#pragma unroll
            for (int m = 0; m < 4; m++)
#pragma unroll
                for (int n = 0; n < 4; n++) {
                    acc[m][n] = __builtin_amdgcn_mfma_f32_16x16x32_bf16(ah[m], bh[n], acc[m][n], 0, 0, 0);
                    acc[m][n] = __builtin_amdgcn_mfma_f32_16x16x32_bf16(ah[m], bl[n], acc[m][n], 0, 0, 0);
                    acc[m][n] = __builtin_amdgcn_mfma_f32_16x16x32_bf16(al[m], bh[n], acc[m][n], 0, 0, 0);
                }
        }
    };

    const int ksteps = K / BKT;      // 8 or 16
    stage(0, 0);
    __syncthreads();
    int cur = 0;
    for (int kt = 0; kt < ksteps - 1; ++kt) {
        stage(cur ^ 1, kt + 1);       // issue next tile first (overlaps compute)
        compute(cur);
        __syncthreads();
        cur ^= 1;
    }
    compute(cur);
    __syncthreads();                  // LDS free for epilogue reuse

    // ---- epilogue ----
    // C/D fragment layout: col=lane&15, row=(lane>>4)*4+j  [guide §3, m89-verified]
    if constexpr (OUTMODE == 2) {
        float* Cf = (float*)C1;
#pragma unroll
        for (int m = 0; m < 4; m++)
#pragma unroll
            for (int n = 0; n < 4; n++) {
                long col = n0 + wc * 64 + n * 16 + lrow;
#pragma unroll
                for (int j = 0; j < 4; j++) {
                    long row = m0 + wr * 64 + m * 16 + kgrp * 4 + j;
                    Cf[(size_t)bz * cBatch + (size_t)row * N + col] = acc[m][n][j];
                }
            }
    } else {
        // scatter acc -> LDS [128][128] u16 with XOR swizzle (bank-spread),
        // then gather 16B/lane coalesced stores.
        u16* sh  = (u16*)lds;            // 32KB
        u16* slo = (u16*)lds + 16384;    // 32KB (OUTMODE 0 only)
#pragma unroll
        for (int m = 0; m < 4; m++) {
#pragma unroll
            for (int n = 0; n < 4; n++) {
                int col_l = wc * 64 + n * 16 + lrow;
                float bv = 0.f;
                if constexpr (BIAS) bv = bias[bz * biasBatch + n0 + col_l];
#pragma unroll
                for (int j = 0; j < 4; j++) {
                    int row_l = wr * 64 + m * 16 + kgrp * 4 + j;
                    int sc = col_l ^ (((row_l >> 2) & 3) << 4);
                    float v = acc[m][n][j];
                    if constexpr (BIAS) v += bv;
                    if constexpr (RELU) v = fmaxf(v, 0.f);
                    if constexpr (OUTMODE == 0) {
                        u16 h = f2bf(v);
                        sh[row_l * 128 + sc]  = h;
                        slo[row_l * 128 + sc] = f2bf(v - bf2f(h));
                    } else {
                        union { f16 f; u16 u; } cv; cv.f = (f16)v;
                        sh[row_l * 128 + sc] = cv.u;
                    }
                }
            }
        }
        __syncthreads();
#pragma unroll
        for (int i = 0; i < 8; i++) {
            int idx = i * 256 + tid;
            int row_l = idx >> 4;            // 0..127
            int c8 = (idx & 15) << 3;        // col start (multiple of 8)
            int sc = c8 ^ (((row_l >> 2) & 3) << 4);
            size_t go = (size_t)bz * cBatch + (size_t)(m0 + row_l) * N + n0 + c8;
            s16x8 vh = *(const s16x8*)&sh[row_l * 128 + sc];
            if constexpr (OUTMODE == 0) {
                s16x8 vl = *(const s16x8*)&slo[row_l * 128 + sc];
                *(s16x8*)&C1[go] = vh;
                *(s16x8*)&C2[go] = vl;
            } else {
                *(s16x8*)&C1[go] = vh;
            }
        }
    }
}

// ---------------- softmax: dist = softmax(10*S/rowmax) ----------------
// fp32 in-place variant (fallback)
__global__ __launch_bounds__(256) void softmax_rows(float* __restrict__ S) {
    const int tid = threadIdx.x;
    float* p = S + (size_t)blockIdx.x * 4096;
    float4 v[4];
    float lmax = -3.4e38f;
#pragma unroll
    for (int i = 0; i < 4; i++) {
        v[i] = ((float4*)p)[tid + 256 * i];
        lmax = fmaxf(lmax, fmaxf(fmaxf(v[i].x, v[i].y), fmaxf(v[i].z, v[i].w)));
    }
#pragma unroll
    for (int o = 32; o; o >>= 1) lmax = fmaxf(lmax, __shfl_xor(lmax, o));
    __shared__ float redm[4];
    __shared__ float reds[4];
    if ((tid & 63) == 0) redm[tid >> 6] = lmax;
    __syncthreads();
    const float m = fmaxf(fmaxf(redm[0], redm[1]), fmaxf(redm[2], redm[3]));
    const float c = 10.0f / m;
    float s = 0.f;
#pragma unroll
    for (int i = 0; i < 4; i++) {
        v[i].x = expf(c * v[i].x - 10.0f);
        v[i].y = expf(c * v[i].y - 10.0f);
        v[i].z = expf(c * v[i].z - 10.0f);
        v[i].w = expf(c * v[i].w - 10.0f);
        s += v[i].x + v[i].y + v[i].z + v[i].w;
    }
#pragma unroll
    for (int o = 32; o; o >>= 1) s += __shfl_xor(s, o);
    if ((tid & 63) == 0) reds[tid >> 6] = s;
    __syncthreads();
    const float inv = 1.0f / (reds[0] + reds[1] + reds[2] + reds[3]);
#pragma unroll
    for (int i = 0; i < 4; i++) {
        v[i].x *= inv; v[i].y *= inv; v[i].z *= inv; v[i].w *= inv;
        ((float4*)p)[tid + 256 * i] = v[i];
    }
}

// fp16-S variant: read fp16 S from ws, write fp32 dist to d_out
__global__ __launch_bounds__(256) void softmax_f16(const f16* __restrict__ S,
                                                   float* __restrict__ O) {
    const int tid = threadIdx.x;
    const f16* p = S + (size_t)blockIdx.x * 4096;
    float* o = O + (size_t)blockIdx.x * 4096;
    f16x8 a0 = ((const f16x8*)p)[tid];          // elements 8*tid ..
    f16x8 a1 = ((const f16x8*)p)[tid + 256];    // elements 8*(tid+256) ..
    float v[16];
#pragma unroll
    for (int j = 0; j < 8; j++) { v[j] = (float)a0[j]; v[8 + j] = (float)a1[j]; }
    float lmax = -3.4e38f;
#pragma unroll
    for (int j = 0; j < 16; j++) lmax = fmaxf(lmax, v[j]);
#pragma unroll
    for (int off = 32; off; off >>= 1) lmax = fmaxf(lmax, __shfl_xor(lmax, off));
    __shared__ float redm[4];
    __shared__ float reds[4];
    if ((tid & 63) == 0) redm[tid >> 6] = lmax;
    __syncthreads();
    const float m = fmaxf(fmaxf(redm[0], redm[1]), fmaxf(redm[2], redm[3]));
    const float c = 10.0f / m;
    float s = 0.f;
#pragma unroll
    for (int j = 0; j < 16; j++) { v[j] = expf(c * v[j] - 10.0f); s += v[j]; }
#pragma unroll
    for (int off = 32; off; off >>= 1) s += __shfl_xor(s, off);
    if ((tid & 63) == 0) reds[tid >> 6] = s;
    __syncthreads();
    const float inv = 1.0f / (reds[0] + reds[1] + reds[2] + reds[3]);
    float4 w;
#pragma unroll
    for (int q = 0; q < 4; q++) {
        int base = q * 4;
        w.x = v[base + 0] * inv; w.y = v[base + 1] * inv;
        w.z = v[base + 2] * inv; w.w = v[base + 3] * inv;
        int idx = (q < 2) ? (2 * tid + q) : (2 * tid + 512 + (q - 2));
        ((float4*)o)[idx] = w;
    }
}

// ---------------- launch ----------------
extern "C" void kernel_launch(void* const* d_in, const int* in_sizes, int n_in,
                              void* d_out, int out_size, void* d_ws, size_t ws_size,
                              hipStream_t stream) {
    const float* x   = (const float*)d_in[0];
    const float* Wq1 = (const float*)d_in[1];
    const float* bq1 = (const float*)d_in[2];
    const float* Wq2 = (const float*)d_in[3];
    const float* bq2 = (const float*)d_in[4];
    const float* Wk1 = (const float*)d_in[5];
    const float* bk1 = (const float*)d_in[6];
    const float* Wk2 = (const float*)d_in[7];
    const float* bk2 = (const float*)d_in[8];
    float* out = (float*)d_out;

    const size_t MB = 1048576;
    char* ws = (char*)d_ws;
    // ws layout: biases | weights | Q/K fp16 | [S fp16]
    float* b1 = (float*)(ws);                    // 4KB
    float* b2 = (float*)(ws + 4096);             // 2KB (reserve to 8KB)
    u16* w1hi = (u16*)(ws + 8 * 1024);           // 512KB
    u16* w1lo = (u16*)(ws + 8 * 1024 + 512 * 1024);
    u16* w2hi = (u16*)(ws + 8 * 1024 + 1024 * 1024);
    u16* w2lo = (u16*)(ws + 8 * 1024 + 1536 * 1024);
    u16* qf   = (u16*)(ws + 4 * MB);             // 8MB fp16 Q
    u16* kf   = (u16*)(ws + 12 * MB);            // 8MB fp16 K (contig after Q)
    f16* S16  = (f16*)(ws + 36 * MB);            // 128MB if available

    const bool f16s = (ws_size >= 164 * MB);

    // d_out doubles as scratch before QK^T/softmax overwrites it:
    char* ob = (char*)d_out;
    u16* xhi = (u16*)(ob + 0 * MB);    // 8MB
    u16* xlo = (u16*)(ob + 8 * MB);    // 8MB
    u16* Hhi = (u16*)(ob + 16 * MB);   // [2][16384][512] = 32MB
    u16* Hlo = (u16*)(ob + 48 * MB);   // 32MB

    split_x_kernel<<<4096, 256, 0, stream>>>(x, xhi, xlo);
    split_wT_kernel<<<dim3(512, 4), 256, 0, stream>>>(Wq1, Wk1, Wq2, Wk2,
                                                      w1hi, w1lo, w2hi, w2lo);
    pack_bias<<<1, 512, 0, stream>>>(bq1, bk1, bq2, bk2, b1, b2);

    // layer 1 (both branches): H = relu(x*W1 + b1), split-bf16 out
    gemm_bt<0, 1, 1, 0><<<dim3(4, 128, 2), 256, 0, stream>>>(
        xhi, xlo, w1hi, w1lo, b1, 512,
        Hhi, Hlo,
        16384, 512, 256,
        0L, 131072L, 8388608L);

    // layer 2 (both branches): Q/K = H*W2 + b2, SINGLE fp16 out (Q then K)
    gemm_bt<0, 1, 0, 1><<<dim3(2, 128, 2), 256, 0, stream>>>(
        Hhi, Hlo, w2hi, w2lo, b2, 256,
        qf, nullptr,
        16384, 256, 512,
        8388608L, 131072L, 4194304L);

    // S = Q*K^T per batch: fp16 A,B, 1 MFMA
    if (f16s) {
        gemm_bt<1, 0, 0, 1><<<dim3(32, 32, 4), 256, 0, stream>>>(
            qf, qf, kf, kf, nullptr, 0,
            (u16*)S16, nullptr,
            4096, 4096, 256,
            1048576L, 1048576L, 16777216L);
        softmax_f16<<<16384, 256, 0, stream>>>(S16, out);
    } else {
        gemm_bt<1, 0, 0, 2><<<dim3(32, 32, 4), 256, 0, stream>>>(
            qf, qf, kf, kf, nullptr, 0,
            (u16*)out, nullptr,
            4096, 4096, 256,
            1048576L, 1048576L, 16777216L);
        softmax_rows<<<16384, 256, 0, stream>>>(out);
    }
}

// Round 11
// 408.211 us; speedup vs baseline: 1.3096x; 1.0565x over previous
//
#include <hip/hip_runtime.h>
#include <hip/hip_bf16.h>

typedef unsigned short u16;
typedef unsigned int u32;
typedef _Float16 f16;
typedef __attribute__((ext_vector_type(4))) float f32x4;
typedef __attribute__((ext_vector_type(4))) _Float16 f16x4;
typedef __attribute__((ext_vector_type(8))) _Float16 f16x8;

__device__ __forceinline__ void gll16(const void* g, void* l) {
    __builtin_amdgcn_global_load_lds(
        (const __attribute__((address_space(1))) void*)g,
        (__attribute__((address_space(3))) void*)l, 16, 0, 0);
}

// ---------------- prep kernels ----------------

// x [4194304] f32 -> fp16, float4-vectorized
__global__ __launch_bounds__(256) void cast_x_kernel(
    const float* __restrict__ x, f16* __restrict__ xf) {
    int i = blockIdx.x * 256 + threadIdx.x;       // < 1048576 (float4 count)
    float4 v = ((const float4*)x)[i];
    f16x4 o;
    o[0] = (f16)v.x; o[1] = (f16)v.y; o[2] = (f16)v.z; o[3] = (f16)v.w;
    ((f16x4*)xf)[i] = o;
}

// transpose + cast the 4 weight matrices into [N][K] fp16 layout
// y=0: Wq1 [256][512] -> w1f + 0       ([512][256])
// y=1: Wk1 [256][512] -> w1f + 131072
// y=2: Wq2 [512][256] -> w2f + 0       ([256][512])
// y=3: Wk2 [512][256] -> w2f + 131072
__global__ __launch_bounds__(256) void cast_wT_kernel(
    const float* __restrict__ Wq1, const float* __restrict__ Wk1,
    const float* __restrict__ Wq2, const float* __restrict__ Wk2,
    f16* __restrict__ w1f, f16* __restrict__ w2f) {
    int y = blockIdx.y;
    const float* src = (y == 0) ? Wq1 : (y == 1) ? Wk1 : (y == 2) ? Wq2 : Wk2;
    int R = (y < 2) ? 256 : 512;   // src rows = K of GEMM
    int C = (y < 2) ? 512 : 256;   // src cols = N of GEMM
    f16* d = ((y < 2) ? w1f : w2f) + (y & 1) * 131072;
    int i = blockIdx.x * 256 + threadIdx.x;       // < 131072
    int c = i / R, r = i - c * R;                 // out[c][r] = src[r][c]
    d[i] = (f16)src[(size_t)r * C + c];
}

__global__ void pack_bias(const float* __restrict__ bq1, const float* __restrict__ bk1,
                          const float* __restrict__ bq2, const float* __restrict__ bk2,
                          float* __restrict__ b1, float* __restrict__ b2) {
    int t = threadIdx.x;                           // 512 threads
    b1[t] = bq1[t]; b1[512 + t] = bk1[t];
    if (t < 256) { b2[t] = bq2[t]; b2[256 + t] = bk2[t]; }
}

// ---------------- fp16 GEMM: C[M,N] = A[M,K] * B[N,K]^T ----------------
// A,B fp16, 1 f16-MFMA per fragment (fp32 accumulate; input-quant ~2.4e-4 rel).
// OUTMODE: 1 = fp16 out via LDS-transposed coalesced stores; 2 = raw fp32.
// BIAS/RELU applied in fp32 before output conversion.
// 2-phase pipelined K-loop (dbuf LDS, BK=32, stage-next-then-compute) —
// LDS-BW-bound structure (confirmed r10): 2 staged matrices is the lever.
#define BM 128
#define BN 128
#define BKT 32

template<int BIAS, int RELU, int OUTMODE>
__global__ __launch_bounds__(256, 2)
void gemm_bt(const f16* __restrict__ A, const f16* __restrict__ B,
             const float* __restrict__ bias, long biasBatch,
             u16* __restrict__ C1,
             int M, int N, int K,
             long aBatch, long bBatch, long cBatch) {
    constexpr int TILEU = BM * BKT;          // 4096 f16 = 8KB per matrix-tile
    constexpr int HALFU = 2 * TILEU;         // A|B per buffer
    __shared__ u16 lds[2 * HALFU];           // 32KB double-buffered

    const int tid = threadIdx.x;
    const int wave = tid >> 6, lane = tid & 63;

    // bijective XCD-aware block swizzle (T1/m204)
    u32 gx = gridDim.x, gy = gridDim.y, gz = gridDim.z;
    u32 flat = (blockIdx.z * gy + blockIdx.y) * gx + blockIdx.x;
    u32 nwg = gx * gy * gz;
    u32 bx, by, bz;
    if ((nwg & 7u) == 0u) {
        u32 cpx = nwg >> 3;
        u32 nf = (flat & 7u) * cpx + (flat >> 3);
        bx = nf % gx; u32 t = nf / gx; by = t % gy; bz = t / gy;
    } else {
        bx = blockIdx.x; by = blockIdx.y; bz = blockIdx.z;
    }

    const long m0 = (long)by * BM, n0 = (long)bx * BN;

    const f16* pA = A + (size_t)bz * aBatch;
    const f16* pB = B + (size_t)bz * bBatch;

    // staging geometry: tile is [128 rows][32 k] f16 = 8KB, linear.
    int srow[2], scol[2];
#pragma unroll
    for (int i = 0; i < 2; i++) {
        int lin = i * 4096 + tid * 16;
        srow[i] = lin >> 6;            // row 0..127 (64B per row)
        scol[i] = (lin & 63) >> 1;     // f16 index 0..31 within row
    }

    const int wr = wave >> 1, wc = wave & 1;
    const int lrow = lane & 15, kgrp = lane >> 4;
    const int ko = kgrp * 8;

    f32x4 acc[4][4] = {};

    auto stage = [&](int b, int kt) {
#pragma unroll
        for (int i = 0; i < 2; i++) {
            size_t ga = (size_t)(m0 + srow[i]) * K + (size_t)kt * BKT + scol[i];
            size_t gb = (size_t)(n0 + srow[i]) * K + (size_t)kt * BKT + scol[i];
            u32 lb = (u32)(b * (HALFU * 2) + i * 4096 + wave * 1024); // bytes
            gll16(pA + ga, (char*)lds + 0 * 8192 + lb);
            gll16(pB + gb, (char*)lds + 1 * 8192 + lb);
        }
    };

    auto compute = [&](int b) {
        const u16* B0 = lds + b * HALFU;
        f16x8 a[4], bb[4];
#pragma unroll
        for (int m = 0; m < 4; m++) {
            int r = wr * 64 + m * 16 + lrow;
            a[m] = *(const f16x8*)&B0[0 * TILEU + r * 32 + ko];
        }
#pragma unroll
        for (int n = 0; n < 4; n++) {
            int r = wc * 64 + n * 16 + lrow;
            bb[n] = *(const f16x8*)&B0[1 * TILEU + r * 32 + ko];
        }
#pragma unroll
        for (int m = 0; m < 4; m++)
#pragma unroll
            for (int n = 0; n < 4; n++)
                acc[m][n] = __builtin_amdgcn_mfma_f32_16x16x32_f16(a[m], bb[n], acc[m][n], 0, 0, 0);
    };

    const int ksteps = K / BKT;      // 8 or 16
    stage(0, 0);
    __syncthreads();
    int cur = 0;
    for (int kt = 0; kt < ksteps - 1; ++kt) {
        stage(cur ^ 1, kt + 1);       // issue next tile first (overlaps compute)
        compute(cur);
        __syncthreads();
        cur ^= 1;
    }
    compute(cur);
    __syncthreads();                  // LDS free for epilogue reuse

    // ---- epilogue ----
    // C/D fragment layout: col=lane&15, row=(lane>>4)*4+j  [guide §3, m89-verified]
    if constexpr (OUTMODE == 2) {
        float* Cf = (float*)C1;
#pragma unroll
        for (int m = 0; m < 4; m++)
#pragma unroll
            for (int n = 0; n < 4; n++) {
                long col = n0 + wc * 64 + n * 16 + lrow;
#pragma unroll
                for (int j = 0; j < 4; j++) {
                    long row = m0 + wr * 64 + m * 16 + kgrp * 4 + j;
                    Cf[(size_t)bz * cBatch + (size_t)row * N + col] = acc[m][n][j];
                }
            }
    } else {
        // scatter acc -> LDS [128][128] u16 with XOR swizzle (bank-spread),
        // then gather 16B/lane coalesced stores. 32KB, exactly the dbuf size.
        u16* sh = (u16*)lds;
#pragma unroll
        for (int m = 0; m < 4; m++) {
#pragma unroll
            for (int n = 0; n < 4; n++) {
                int col_l = wc * 64 + n * 16 + lrow;
                float bv = 0.f;
                if constexpr (BIAS) bv = bias[bz * biasBatch + n0 + col_l];
#pragma unroll
                for (int j = 0; j < 4; j++) {
                    int row_l = wr * 64 + m * 16 + kgrp * 4 + j;
                    int sc = col_l ^ (((row_l >> 2) & 3) << 4);
                    float v = acc[m][n][j];
                    if constexpr (BIAS) v += bv;
                    if constexpr (RELU) v = fmaxf(v, 0.f);
                    union { f16 f; u16 u; } cv; cv.f = (f16)v;
                    sh[row_l * 128 + sc] = cv.u;
                }
            }
        }
        __syncthreads();
#pragma unroll
        for (int i = 0; i < 8; i++) {
            int idx = i * 256 + tid;
            int row_l = idx >> 4;            // 0..127
            int c8 = (idx & 15) << 3;        // col start (multiple of 8)
            int sc = c8 ^ (((row_l >> 2) & 3) << 4);
            size_t go = (size_t)bz * cBatch + (size_t)(m0 + row_l) * N + n0 + c8;
            *(f16x8*)&C1[go] = *(const f16x8*)&sh[row_l * 128 + sc];
        }
    }
}

// ---------------- softmax: dist = softmax(10*S/rowmax) ----------------
// fp32 in-place variant (fallback)
__global__ __launch_bounds__(256) void softmax_rows(float* __restrict__ S) {
    const int tid = threadIdx.x;
    float* p = S + (size_t)blockIdx.x * 4096;
    float4 v[4];
    float lmax = -3.4e38f;
#pragma unroll
    for (int i = 0; i < 4; i++) {
        v[i] = ((float4*)p)[tid + 256 * i];
        lmax = fmaxf(lmax, fmaxf(fmaxf(v[i].x, v[i].y), fmaxf(v[i].z, v[i].w)));
    }
#pragma unroll
    for (int o = 32; o; o >>= 1) lmax = fmaxf(lmax, __shfl_xor(lmax, o));
    __shared__ float redm[4];
    __shared__ float reds[4];
    if ((tid & 63) == 0) redm[tid >> 6] = lmax;
    __syncthreads();
    const float m = fmaxf(fmaxf(redm[0], redm[1]), fmaxf(redm[2], redm[3]));
    const float c = 10.0f / m;
    float s = 0.f;
#pragma unroll
    for (int i = 0; i < 4; i++) {
        v[i].x = expf(c * v[i].x - 10.0f);
        v[i].y = expf(c * v[i].y - 10.0f);
        v[i].z = expf(c * v[i].z - 10.0f);
        v[i].w = expf(c * v[i].w - 10.0f);
        s += v[i].x + v[i].y + v[i].z + v[i].w;
    }
#pragma unroll
    for (int o = 32; o; o >>= 1) s += __shfl_xor(s, o);
    if ((tid & 63) == 0) reds[tid >> 6] = s;
    __syncthreads();
    const float inv = 1.0f / (reds[0] + reds[1] + reds[2] + reds[3]);
#pragma unroll
    for (int i = 0; i < 4; i++) {
        v[i].x *= inv; v[i].y *= inv; v[i].z *= inv; v[i].w *= inv;
        ((float4*)p)[tid + 256 * i] = v[i];
    }
}

// fp16-S variant: read fp16 S from ws, write fp32 dist to d_out
__global__ __launch_bounds__(256) void softmax_f16(const f16* __restrict__ S,
                                                   float* __restrict__ O) {
    const int tid = threadIdx.x;
    const f16* p = S + (size_t)blockIdx.x * 4096;
    float* o = O + (size_t)blockIdx.x * 4096;
    f16x8 a0 = ((const f16x8*)p)[tid];          // elements 8*tid ..
    f16x8 a1 = ((const f16x8*)p)[tid + 256];    // elements 8*(tid+256) ..
    float v[16];
#pragma unroll
    for (int j = 0; j < 8; j++) { v[j] = (float)a0[j]; v[8 + j] = (float)a1[j]; }
    float lmax = -3.4e38f;
#pragma unroll
    for (int j = 0; j < 16; j++) lmax = fmaxf(lmax, v[j]);
#pragma unroll
    for (int off = 32; off; off >>= 1) lmax = fmaxf(lmax, __shfl_xor(lmax, off));
    __shared__ float redm[4];
    __shared__ float reds[4];
    if ((tid & 63) == 0) redm[tid >> 6] = lmax;
    __syncthreads();
    const float m = fmaxf(fmaxf(redm[0], redm[1]), fmaxf(redm[2], redm[3]));
    const float c = 10.0f / m;
    float s = 0.f;
#pragma unroll
    for (int j = 0; j < 16; j++) { v[j] = expf(c * v[j] - 10.0f); s += v[j]; }
#pragma unroll
    for (int off = 32; off; off >>= 1) s += __shfl_xor(s, off);
    if ((tid & 63) == 0) reds[tid >> 6] = s;
    __syncthreads();
    const float inv = 1.0f / (reds[0] + reds[1] + reds[2] + reds[3]);
    float4 w;
#pragma unroll
    for (int q = 0; q < 4; q++) {
        int base = q * 4;
        w.x = v[base + 0] * inv; w.y = v[base + 1] * inv;
        w.z = v[base + 2] * inv; w.w = v[base + 3] * inv;
        int idx = (q < 2) ? (2 * tid + q) : (2 * tid + 512 + (q - 2));
        ((float4*)o)[idx] = w;
    }
}

// ---------------- launch ----------------
extern "C" void kernel_launch(void* const* d_in, const int* in_sizes, int n_in,
                              void* d_out, int out_size, void* d_ws, size_t ws_size,
                              hipStream_t stream) {
    const float* x   = (const float*)d_in[0];
    const float* Wq1 = (const float*)d_in[1];
    const float* bq1 = (const float*)d_in[2];
    const float* Wq2 = (const float*)d_in[3];
    const float* bq2 = (const float*)d_in[4];
    const float* Wk1 = (const float*)d_in[5];
    const float* bk1 = (const float*)d_in[6];
    const float* Wk2 = (const float*)d_in[7];
    const float* bk2 = (const float*)d_in[8];
    float* out = (float*)d_out;

    const size_t MB = 1048576;
    char* ws = (char*)d_ws;
    // ws layout: biases | weights fp16 | Q/K fp16 | [S fp16]
    float* b1 = (float*)(ws);                    // 4KB
    float* b2 = (float*)(ws + 4096);             // 2KB (reserve to 8KB)
    f16* w1f  = (f16*)(ws + 8 * 1024);           // 512KB  [2][512][256]
    f16* w2f  = (f16*)(ws + 8 * 1024 + 512 * 1024); // 512KB [2][256][512]
    f16* qf   = (f16*)(ws + 4 * MB);             // 8MB fp16 Q [4][4096][256]
    f16* kf   = (f16*)(ws + 12 * MB);            // 8MB fp16 K (contig after Q)
    f16* S16  = (f16*)(ws + 36 * MB);            // 128MB if available

    const bool f16s = (ws_size >= 164 * MB);

    // d_out doubles as scratch before QK^T/softmax overwrites it:
    char* ob = (char*)d_out;
    f16* xf = (f16*)(ob + 0 * MB);     // 8MB
    f16* Hf = (f16*)(ob + 16 * MB);    // [2][16384][512] fp16 = 32MB

    cast_x_kernel<<<4096, 256, 0, stream>>>(x, xf);
    cast_wT_kernel<<<dim3(512, 4), 256, 0, stream>>>(Wq1, Wk1, Wq2, Wk2, w1f, w2f);
    pack_bias<<<1, 512, 0, stream>>>(bq1, bk1, bq2, bk2, b1, b2);

    // layer 1 (both branches): H = relu(x*W1 + b1), fp16 out
    gemm_bt<1, 1, 1><<<dim3(4, 128, 2), 256, 0, stream>>>(
        xf, w1f, b1, 512,
        (u16*)Hf,
        16384, 512, 256,
        0L, 131072L, 8388608L);

    // layer 2 (both branches): Q/K = H*W2 + b2, fp16 out (Q then K in ws)
    gemm_bt<1, 0, 1><<<dim3(2, 128, 2), 256, 0, stream>>>(
        Hf, w2f, b2, 256,
        (u16*)qf,
        16384, 256, 512,
        8388608L, 131072L, 4194304L);

    // S = Q*K^T per batch: fp16 A,B, 1 MFMA
    if (f16s) {
        gemm_bt<0, 0, 1><<<dim3(32, 32, 4), 256, 0, stream>>>(
            qf, kf, nullptr, 0,
            (u16*)S16,
            4096, 4096, 256,
            1048576L, 1048576L, 16777216L);
        softmax_f16<<<16384, 256, 0, stream>>>(S16, out);
    } else {
        gemm_bt<0, 0, 2><<<dim3(32, 32, 4), 256, 0, stream>>>(
            qf, kf, nullptr, 0,
            (u16*)out,
            4096, 4096, 256,
            1048576L, 1048576L, 16777216L);
        softmax_rows<<<16384, 256, 0, stream>>>(out);
    }
}